// Round 1
// 6564.595 us; speedup vs baseline: 1.0340x; 1.0340x over previous
//
#include <hip/hip_runtime.h>
#include <stdint.h>
#include <math.h>

// ---------------------------------------------------------------------------
// GausskeyL2P: ViT-B/16 x2 passes + MVN gaussian-key prompt selection.
// Round 4: qkv (N=2304) and fc1 (N=3072) GEMMs moved from the single-buffered
// 2-barrier 128-tile hgemm_t to a 256x256 8-phase counted-vmcnt template
// (T2 conflict-free k-half-major LDS + XOR swizzle, T3+T4 vmcnt(8) pipeline,
// T5 setprio). Raw s_barrier everywhere in the new kernel -- no vmcnt(0)
// drains in the K-loop. proj/fc2/patch stay on hgemm_t (N=768 -> too few
// 256-wide column tiles).
// ---------------------------------------------------------------------------

typedef _Float16 h16_t;
typedef _Float16 h8v __attribute__((ext_vector_type(8)));
typedef _Float16 h4v __attribute__((ext_vector_type(4)));
typedef float    f4v __attribute__((ext_vector_type(4)));

#define DEV static __device__ __forceinline__

DEV float wred64(float s) {
#pragma unroll
  for (int m = 1; m < 64; m <<= 1) s += __shfl_xor(s, m, 64);
  return s;
}
DEV float gelu_f(float x) {  // jax.nn.gelu approximate=True (tanh form)
  float u = 0.7978845608028654f * x * (1.0f + 0.044715f * x * x);
  u = fminf(fmaxf(u, -30.0f), 30.0f);
  float e = __expf(-2.0f * u);
  return 0.5f * x * (1.0f + (1.0f - e) / (1.0f + e));
}

#define GLD16(gp, lp) __builtin_amdgcn_global_load_lds( \
  (const __attribute__((address_space(1))) unsigned int*)(const void*)(gp), \
  (__attribute__((address_space(3))) unsigned int*)(void*)(lp), 16, 0, 0)

// ---------------------------------------------------------------------------
// fp16 MFMA GEMM: C = act(alpha*A*B^T + bias) [+C32]; A[M,K] lda, B[N,K] ldb.
// 128x(TJ*32) tile, BK=32, 256 thr (4 waves). TJ=2: wave 64x32 -- used for
// N=768 GEMMs (proj, fc2, patch embed).
// ---------------------------------------------------------------------------
template <int TJ>
__global__ __launch_bounds__(256) void hgemm_t(
    const h16_t* __restrict__ A, const h16_t* __restrict__ B,
    float* __restrict__ C32, h16_t* __restrict__ C16,
    const float* __restrict__ bias,
    int M, int N, int K, int lda, int ldb, int ldc32, int ldc16,
    float alpha, int act, int addC)
{
  constexpr int BN = TJ * 32;
  __shared__ __align__(16) h16_t As[128 * 32];
  __shared__ __align__(16) h16_t Bs[BN * 32];
  int tid = threadIdx.x;
  int w = tid >> 6, lane = tid & 63;
  int m0 = blockIdx.x << 7, n0 = blockIdx.y * BN;
  int qm = (w & 1) << 6, qn = (w >> 1) * (TJ * 16);
  int scol = (lane & 3) << 3;
  int fr = lane & 15, fk = (lane >> 4) << 3;

  f4v acc[4][TJ];
#pragma unroll
  for (int i = 0; i < 4; i++)
#pragma unroll
    for (int j = 0; j < TJ; j++)
#pragma unroll
      for (int r = 0; r < 4; r++) acc[i][j][r] = 0.0f;

  for (int k0 = 0; k0 < K; k0 += 32) {
    __syncthreads();
#pragma unroll
    for (int i = 0; i < 2; i++) {
      int rr = (w << 5) + (i << 4) + (lane >> 2);
      int gm = m0 + rr; gm = gm < M ? gm : M - 1;
      GLD16(A + (size_t)gm * lda + k0 + scol, &As[((w << 5) + (i << 4)) << 5]);
    }
#pragma unroll
    for (int i = 0; i < TJ / 2; i++) {
      int rb = w * (TJ / 2) * 16 + i * 16;
      int rr = rb + (lane >> 2);
      int gn = n0 + rr; gn = gn < N ? gn : N - 1;
      GLD16(B + (size_t)gn * ldb + k0 + scol, &Bs[rb << 5]);
    }
    __syncthreads();
    h8v af[4], bf[TJ];
#pragma unroll
    for (int t = 0; t < 4; t++)
      af[t] = *(const h8v*)&As[((qm + (t << 4) + fr) << 5) + fk];
#pragma unroll
    for (int t = 0; t < TJ; t++)
      bf[t] = *(const h8v*)&Bs[((qn + (t << 4) + fr) << 5) + fk];
#pragma unroll
    for (int ti = 0; ti < 4; ti++)
#pragma unroll
      for (int tj = 0; tj < TJ; tj++)
        acc[ti][tj] = __builtin_amdgcn_mfma_f32_16x16x32_f16(af[ti], bf[tj], acc[ti][tj], 0, 0, 0);
  }

  int colb = n0 + qn + fr;
  int rowb = m0 + qm + ((lane >> 4) << 2);
#pragma unroll
  for (int tj = 0; tj < TJ; tj++) {
    int col = colb + (tj << 4);
    if (col >= N) continue;
    float bv = (bias != nullptr) ? bias[col] : 0.0f;
#pragma unroll
    for (int ti = 0; ti < 4; ti++) {
#pragma unroll
      for (int rg = 0; rg < 4; rg++) {
        int row = rowb + (ti << 4) + rg;
        if (row >= M) continue;
        float v = alpha * acc[ti][tj][rg] + bv;
        if (act) v = gelu_f(v);
        if (C32) {
          size_t off = (size_t)row * ldc32 + col;
          if (addC) v += C32[off];
          C32[off] = v;
        }
        if (C16) C16[(size_t)row * ldc16 + col] = (h16_t)v;
      }
    }
  }
}

// ---------------------------------------------------------------------------
// 256x256 8-phase fp16 GEMM, C16 = act(A*B^T + bias). A[M,K] fp16 (ld=K),
// B[N,K] fp16 (ld=K), N % 256 == 0, K % 64 == 0, K >= 128.
// 512 thr (8 waves, 2M x 4N), BK=64 K-tiles double-buffered in 128 KiB LDS.
// LDS layout per operand per K-tile: [2 khalf][256 rows][32 k] fp16 (64 B
// rows), with involutive XOR swizzle P ^= ((P>>7)&3)<<4 applied to BOTH the
// pre-swizzled global source and the ds_read address (linear GLD dest).
// Schedule per iteration i (compute K-tile i from buf[i&1]):
//   ph1: frags(kh0,M0-3) | stage A(i+1,kh1)->buf[o] | BAR | 16 MFMA | BAR
//   ph2: frags(kh0,M4-7) | stage B(i+1,kh1)->buf[o] | BAR | 16 MFMA | vmcnt(8) BAR
//   ph3: frags(kh1,M0-3) | stage A(i+2,kh0)->buf[c] | BAR | 16 MFMA | BAR
//   ph4: frags(kh1,M4-7) | stage B(i+2,kh0)->buf[c] | BAR | 16 MFMA | vmcnt(8) BAR
// Stage targets are always regions whose reads drained (per-wave lgkmcnt)
// before the preceding end-barrier; vmcnt(8) leaves exactly the newest 4
// stages (8 instr) in flight, confirming the half-tiles read 2 phases later.
// Tail iterations re-stage clamped K-tile NT-1 (never read) so the vmcnt
// counting stays uniform.
// ---------------------------------------------------------------------------
DEV void stg8(const h16_t* __restrict__ src, int row0, int rowmax, int ldk,
              char* ldsb, unsigned lbase, int tid) {
#pragma unroll
  for (int r = 0; r < 2; r++) {
    unsigned P = ((unsigned)r << 13) + ((unsigned)tid << 4);
    unsigned Q = P ^ (((P >> 7) & 3u) << 4);
    int row = (int)(Q >> 6);
    int kb = (int)((Q & 63u) >> 1);
    int gr = row0 + row; gr = gr < rowmax ? gr : rowmax - 1;
    GLD16(src + (size_t)gr * ldk + kb,
          ldsb + lbase + (r << 13) + ((tid >> 6) << 10));
  }
}

#define FENCE() asm volatile("" ::: "memory")
#define RBAR() do { FENCE(); __builtin_amdgcn_s_barrier(); FENCE(); } while (0)
#define VM8() asm volatile("s_waitcnt vmcnt(8)" ::: "memory")

#define LOADFRAGS(S, G) do { \
  unsigned ab_ = cb + ((unsigned)(S) << 14); \
  unsigned bb_ = cb + 32768u + ((unsigned)(S) << 14); \
  _Pragma("unroll") for (int t = 0; t < 4; t++) { \
    unsigned PA_ = ((unsigned)((wm << 7) + ((G) << 6) + (t << 4) + fr) << 6) + ((unsigned)quad << 4); \
    PA_ ^= ((PA_ >> 7) & 3u) << 4; \
    af[t] = *(const h8v*)(ldsb + ab_ + PA_); \
    unsigned PB_ = ((unsigned)((wn << 6) + (t << 4) + fr) << 6) + ((unsigned)quad << 4); \
    PB_ ^= ((PB_ >> 7) & 3u) << 4; \
    bf[t] = *(const h8v*)(ldsb + bb_ + PB_); \
  } } while (0)

#define MM8(G) do { \
  __builtin_amdgcn_s_setprio(1); \
  _Pragma("unroll") for (int ti = 0; ti < 4; ti++) \
  _Pragma("unroll") for (int tj = 0; tj < 4; tj++) \
    acc[((G) << 2) + ti][tj] = __builtin_amdgcn_mfma_f32_16x16x32_f16(af[ti], bf[tj], acc[((G) << 2) + ti][tj], 0, 0, 0); \
  __builtin_amdgcn_s_setprio(0); } while (0)

template <int ACT>
__global__ __launch_bounds__(512, 2) void hgemm8(
    const h16_t* __restrict__ A, const h16_t* __restrict__ B,
    h16_t* __restrict__ C16, const float* __restrict__ bias,
    int M, int N, int K, int ldc16)
{
  __shared__ __align__(16) char ldsb[131072];
  int tid = threadIdx.x;
  int w = tid >> 6, lane = tid & 63;
  int wm = w >> 2, wn = w & 3;
  int fr = lane & 15, quad = lane >> 4;
  int m0 = blockIdx.x << 8, n0 = blockIdx.y << 8;

  f4v acc[8][4];
#pragma unroll
  for (int i2 = 0; i2 < 8; i2++)
#pragma unroll
    for (int j2 = 0; j2 < 4; j2++)
#pragma unroll
      for (int r2 = 0; r2 < 4; r2++) acc[i2][j2][r2] = 0.0f;

  int NT = K >> 6;

  // prologue: K-tile 0 fully, K-tile 1 khalf0, into buf0/buf1
  stg8(A,      m0, M, K, ldsb, 0u,              tid);   // A(0,kh0)
  stg8(B,      n0, N, K, ldsb, 32768u,          tid);   // B(0,kh0)
  stg8(A + 32, m0, M, K, ldsb, 16384u,          tid);   // A(0,kh1)
  stg8(B + 32, n0, N, K, ldsb, 32768u + 16384u, tid);   // B(0,kh1)
  stg8(A + 64, m0, M, K, ldsb, 65536u,          tid);   // A(1,kh0)
  stg8(B + 64, n0, N, K, ldsb, 65536u + 32768u, tid);   // B(1,kh0)
  VM8();                       // first 2 stages (A/B(0,kh0)) landed
  __builtin_amdgcn_s_barrier();
  FENCE();

  for (int i = 0; i < NT; i++) {
    unsigned cb = (unsigned)(i & 1) << 16;
    unsigned ob = cb ^ 65536u;
    int tA = (i + 1 < NT) ? i + 1 : NT - 1;
    int tB = (i + 2 < NT) ? i + 2 : NT - 1;
    h8v af[4], bf[4];

    // ---- phase 1: kh0, M-frags 0-3; stage A(i+1,kh1) -> buf[o]
    LOADFRAGS(0, 0);
    stg8(A + (tA << 6) + 32, m0, M, K, ldsb, ob + 16384u, tid);
    RBAR();
    MM8(0);
    RBAR();
    // ---- phase 2: kh0, M-frags 4-7; stage B(i+1,kh1) -> buf[o]
    LOADFRAGS(0, 1);
    stg8(B + (tA << 6) + 32, n0, N, K, ldsb, ob + 49152u, tid);
    RBAR();
    MM8(1);
    VM8();   // confirms A/B(i,kh1) landed (needed by phases 3/4)
    RBAR();
    // ---- phase 3: kh1, M-frags 0-3; stage A(i+2,kh0) -> buf[c]
    LOADFRAGS(1, 0);
    stg8(A + (tB << 6), m0, M, K, ldsb, cb, tid);
    RBAR();
    MM8(0);
    RBAR();
    // ---- phase 4: kh1, M-frags 4-7; stage B(i+2,kh0) -> buf[c]
    LOADFRAGS(1, 1);
    stg8(B + (tB << 6), n0, N, K, ldsb, cb + 32768u, tid);
    RBAR();
    MM8(1);
    VM8();   // confirms A/B(i+1,kh0) landed (needed by next iter ph1/2)
    RBAR();
  }
  asm volatile("s_waitcnt vmcnt(0)" ::: "memory");  // drain before LDS dealloc

  // epilogue: C[row][col] = act(acc + bias[col]); col always < N (N%256==0)
  int row0 = m0 + (wm << 7) + (quad << 2);
  int col0 = n0 + (wn << 6) + fr;
  float bv[4];
#pragma unroll
  for (int nj = 0; nj < 4; nj++) bv[nj] = bias[col0 + (nj << 4)];
#pragma unroll
  for (int mi = 0; mi < 8; mi++) {
#pragma unroll
    for (int rg = 0; rg < 4; rg++) {
      int row = row0 + (mi << 4) + rg;
      if (row < M) {
#pragma unroll
        for (int nj = 0; nj < 4; nj++) {
          float v = acc[mi][nj][rg] + bv[nj];
          if (ACT) v = gelu_f(v);
          C16[(size_t)row * ldc16 + col0 + (nj << 4)] = (h16_t)v;
        }
      }
    }
  }
}

// ---------------------------------------------------------------------------
// Fused flash attention: qkv16 [B*N, 2304] fp16 (bias applied) -> o [B*N,768]
// grid (ceil(N/64), B*12), 256 thr.
// ---------------------------------------------------------------------------
__global__ __launch_bounds__(256) void flash_attn(
    const h16_t* __restrict__ qkv, h16_t* __restrict__ o, int N)
{
  int z = blockIdx.y;
  int b = z / 12, h = z - (z / 12) * 12;
  const h16_t* base = qkv + (size_t)b * N * 2304 + h * 64;
  int q0 = blockIdx.x << 6;
  int tid = threadIdx.x, w = tid >> 6, lane = tid & 63;
  int fr = lane & 15, fk = (lane >> 4) << 3;
  int quad = lane >> 4;

  __shared__ __align__(16) h16_t Qs[2][64 * 32];
  __shared__ __align__(16) h16_t Ks[2][64 * 32];
  __shared__ __align__(16) h16_t Ps[4][1024];
  __shared__ __align__(16) h16_t Vt[64 * 68];

#pragma unroll
  for (int s = 0; s < 2; s++) {
    int gq = q0 + (w << 4) + (lane >> 2); gq = gq < N ? gq : N - 1;
    GLD16(base + (size_t)gq * 2304 + (s << 5) + ((lane & 3) << 3), &Qs[s][(w << 4) << 5]);
  }
  __syncthreads();
  h8v af0 = *(const h8v*)&Qs[0][(((w << 4) + fr) << 5) + fk];
  h8v af1 = *(const h8v*)&Qs[1][(((w << 4) + fr) << 5) + fk];

  float mrow[4], lrow[4];
  f4v accO[4];
#pragma unroll
  for (int r = 0; r < 4; r++) { mrow[r] = -1e30f; lrow[r] = 0.0f; }
#pragma unroll
  for (int t = 0; t < 4; t++)
#pragma unroll
    for (int r = 0; r < 4; r++) accO[t][r] = 0.0f;

  int nj = (N + 63) >> 6;
  for (int jt = 0; jt < nj; jt++) {
    int j0 = jt << 6;
    __syncthreads();
#pragma unroll
    for (int s = 0; s < 2; s++) {
      int gj = j0 + (w << 4) + (lane >> 2); gj = gj < N ? gj : N - 1;
      GLD16(base + (size_t)gj * 2304 + 768 + (s << 5) + ((lane & 3) << 3), &Ks[s][(w << 4) << 5]);
    }
#pragma unroll
    for (int i = 0; i < 16; i++) {
      int j = (w << 4) + i;
      int gj = j0 + j; gj = gj < N ? gj : N - 1;
      Vt[lane * 68 + j] = base[(size_t)gj * 2304 + 1536 + lane];
    }
    __syncthreads();

    f4v s4[4];
#pragma unroll
    for (int t = 0; t < 4; t++) {
      h8v b0 = *(const h8v*)&Ks[0][(((t << 4) + fr) << 5) + fk];
      h8v b1 = *(const h8v*)&Ks[1][(((t << 4) + fr) << 5) + fk];
      f4v s; s[0] = s[1] = s[2] = s[3] = 0.0f;
      s = __builtin_amdgcn_mfma_f32_16x16x32_f16(af0, b0, s, 0, 0, 0);
      s = __builtin_amdgcn_mfma_f32_16x16x32_f16(af1, b1, s, 0, 0, 0);
      s4[t] = s;
    }
#pragma unroll
    for (int r = 0; r < 4; r++) {
      float tm = -1e30f;
#pragma unroll
      for (int t = 0; t < 4; t++) {
        float v = s4[t][r] * 0.125f;
        if (j0 + (t << 4) + fr >= N) v = -1e30f;
        s4[t][r] = v;
        tm = fmaxf(tm, v);
      }
#pragma unroll
      for (int m = 1; m < 16; m <<= 1) tm = fmaxf(tm, __shfl_xor(tm, m, 64));
      float mn = fmaxf(mrow[r], tm);
      float alpha = __expf(mrow[r] - mn);
      mrow[r] = mn;
      float rs = 0.0f;
#pragma unroll
      for (int t = 0; t < 4; t++) {
        float e = __expf(s4[t][r] - mn);
        s4[t][r] = e;
        rs += e;
      }
#pragma unroll
      for (int m = 1; m < 16; m <<= 1) rs += __shfl_xor(rs, m, 64);
      lrow[r] = lrow[r] * alpha + rs;
#pragma unroll
      for (int t = 0; t < 4; t++) accO[t][r] *= alpha;
#pragma unroll
      for (int t = 0; t < 4; t++)
        Ps[w][((t >> 1) << 9) + (((quad << 2) + r) << 5) + ((t & 1) << 4) + fr] = (h16_t)s4[t][r];
    }
#pragma unroll
    for (int s = 0; s < 2; s++) {
      h8v ap = *(const h8v*)&Ps[w][(s << 9) + (fr << 5) + fk];
#pragma unroll
      for (int t = 0; t < 4; t++) {
        int vidx = ((t << 4) + fr) * 68 + (s << 5) + fk;
        h4v v0 = *(const h4v*)&Vt[vidx];
        h4v v1 = *(const h4v*)&Vt[vidx + 4];
        h8v bv;
#pragma unroll
        for (int i = 0; i < 4; i++) { bv[i] = v0[i]; bv[i + 4] = v1[i]; }
        accO[t] = __builtin_amdgcn_mfma_f32_16x16x32_f16(ap, bv, accO[t], 0, 0, 0);
      }
    }
  }

#pragma unroll
  for (int r = 0; r < 4; r++) {
    int q = q0 + (w << 4) + (quad << 2) + r;
    if (q >= N) continue;
    float inv = 1.0f / lrow[r];
    h16_t* op = o + ((size_t)b * N + q) * 768 + h * 64 + fr;
#pragma unroll
    for (int t = 0; t < 4; t++) op[t << 4] = (h16_t)(accO[t][r] * inv);
  }
}

// ---------------- weight convert: fp32 [K,N] -> fp16 [N,K] (batched z) ------
__global__ __launch_bounds__(256) void wcvt_t(const float* __restrict__ in,
                                              h16_t* __restrict__ o, int K, int N) {
  int z = blockIdx.z;
  in += (size_t)z * K * N;
  o  += (size_t)z * K * N;
  int n0 = blockIdx.x << 5, k0 = blockIdx.y << 5;
  __shared__ float t[32][33];
  int a = threadIdx.x >> 3, b4 = (threadIdx.x & 7) << 2;
  f4v v = *(const f4v*)(in + (size_t)(k0 + a) * N + n0 + b4);
  t[a][b4] = v[0]; t[a][b4 + 1] = v[1]; t[a][b4 + 2] = v[2]; t[a][b4 + 3] = v[3];
  __syncthreads();
  h4v h;
#pragma unroll
  for (int i = 0; i < 4; i++) h[i] = (h16_t)t[b4 + i][a];
  *(h4v*)(o + (size_t)(n0 + a) * K + k0 + b4) = h;
}

__global__ void cvt_flat(const float* __restrict__ in, h16_t* __restrict__ o, int n) {
  int i = blockIdx.x * 256 + threadIdx.x;
  if (i < n) o[i] = (h16_t)in[i];
}

// ---------------- patch embed im2col (fp16 out) -----------------------------
__global__ void im2col_k(const float* __restrict__ in, h16_t* __restrict__ col) {
  int idx = blockIdx.x * 256 + threadIdx.x;
  if (idx >= 16 * 196 * 768) return;
  int k = idx % 768; int t = idx / 768; int p2 = t % 196; int b = t / 196;
  int c = k >> 8, ij = k & 255, i = ij >> 4, j = ij & 15;
  int py = p2 / 14, px = p2 % 14;
  col[idx] = (h16_t)in[(((size_t)b * 3 + c) * 224 + py * 16 + i) * 224 + px * 16 + j];
}

__global__ void build_x0_k(float* __restrict__ x, const float* __restrict__ img,
                           const float* __restrict__ cls, const float* __restrict__ pos) {
  int idx = blockIdx.x * 256 + threadIdx.x;
  if (idx >= 16 * 197 * 768) return;
  int d = idx % 768; int t = idx / 768; int n = t % 197; int b = t / 197;
  float v = (n == 0) ? cls[d] : img[((size_t)b * 196 + (n - 1)) * 768 + d];
  x[idx] = v + pos[n * 768 + d];
}

__global__ void build_x2_k(float* __restrict__ x, const float* __restrict__ img,
                           const float* __restrict__ cls, const float* __restrict__ pos,
                           const float* __restrict__ prompt, const int* __restrict__ tk) {
  int idx = blockIdx.x * 256 + threadIdx.x;
  if (idx >= 16 * 222 * 768) return;
  int d = idx % 768; int t = idx / 768; int n = t % 222; int b = t / 222;
  float v;
  if (n == 0) v = cls[d] + pos[d];
  else if (n < 26) {
    int s = (n - 1) / 5, li = (n - 1) % 5;
    v = prompt[((size_t)tk[b * 5 + s] * 5 + li) * 768 + d] + pos[d];
  } else {
    v = img[((size_t)b * 196 + (n - 26)) * 768 + d];
  }
  x[idx] = v;
}

// ---------------- LayerNorm rows (wave per row), fp16 and/or fp32 out -------
__global__ void ln_rows(const float* __restrict__ in, h16_t* __restrict__ o16,
                        float* __restrict__ o32, const float* __restrict__ g,
                        const float* __restrict__ b, int rows, long istr, long ostr) {
  int gw = ((blockIdx.x << 8) + threadIdx.x) >> 6;
  int lane = threadIdx.x & 63;
  if (gw >= rows) return;
  const float* rp = in + (size_t)gw * istr;
  float v[12]; float s = 0;
#pragma unroll
  for (int i = 0; i < 12; i++) { v[i] = rp[lane + (i << 6)]; s += v[i]; }
  s = wred64(s);
  float mean = s * (1.0f / 768.0f);
  float s2 = 0;
#pragma unroll
  for (int i = 0; i < 12; i++) { float d = v[i] - mean; s2 += d * d; }
  s2 = wred64(s2);
  float rstd = rsqrtf(s2 * (1.0f / 768.0f) + 1e-6f);
#pragma unroll
  for (int i = 0; i < 12; i++) {
    int k = lane + (i << 6);
    float o = (v[i] - mean) * rstd * g[k] + b[k];
    if (o16) o16[(size_t)gw * ostr + k] = (h16_t)o;
    if (o32) o32[(size_t)gw * ostr + k] = o;
  }
}

// ---------------- Cholesky: cov init, NT update GEMM, panel factor ----------
__global__ void cov_init_k(const float* __restrict__ var, float* __restrict__ Lb) {
  size_t i = (size_t)blockIdx.x * 256 + threadIdx.x;
  if (i >= (size_t)10 * 589824) return;
  int ij = (int)(i % 589824);
  int r = ij / 768, c = ij - r * 768;
  Lb[i] = fabsf(var[i]) + ((r == c) ? 1.0f : 0.0f);
}

__global__ __launch_bounds__(256) void sgemm_nt_chol(float* __restrict__ Lb, int jb) {
  int p = blockIdx.z;
  float* base = Lb + (size_t)p * 589824;
  const float* A = base + (size_t)jb * 768;
  const float* Bp = A;
  float* C = base + (size_t)jb * 768 + jb;
  int m0 = blockIdx.x << 6;
  __shared__ float As[16][64];
  __shared__ float Bs[16][64];
  int tid = threadIdx.x;
  int am = tid & 63, ak = (tid >> 6) << 2;
  int tm = (tid >> 4) << 2, tn = (tid & 15) << 2;
  float acc[4][4] = {};
  for (int k0 = 0; k0 < jb; k0 += 16) {
    f4v va = *(const f4v*)(A + (size_t)(m0 + am) * 768 + k0 + ak);
    f4v vb = *(const f4v*)(Bp + (size_t)am * 768 + k0 + ak);
#pragma unroll
    for (int i = 0; i < 4; i++) { As[ak + i][am] = va[i]; Bs[ak + i][am] = vb[i]; }
    __syncthreads();
#pragma unroll
    for (int kk = 0; kk < 16; kk++) {
      f4v a = *(const f4v*)&As[kk][tm];
      f4v b = *(const f4v*)&Bs[kk][tn];
#pragma unroll
      for (int i = 0; i < 4; i++)
#pragma unroll
        for (int j = 0; j < 4; j++) acc[i][j] += a[i] * b[j];
    }
    __syncthreads();
  }
#pragma unroll
  for (int i = 0; i < 4; i++)
#pragma unroll
    for (int j = 0; j < 4; j++)
      C[(size_t)(m0 + tm + i) * 768 + tn + j] -= acc[i][j];
}

template <int CB>
DEV void chol_sub(float (&row)[64], int r, bool actv, float* Bl, float* Dg, float* Dinv) {
  if constexpr (CB > 0) {
    if (actv && r >= CB && r < CB + 16) {
      int c = r - CB;
#pragma unroll
      for (int k = 0; k < CB; k++) Bl[k * 16 + c] = row[k];
    }
    __syncthreads();
    if (actv && r >= CB) {
#pragma unroll
      for (int k = 0; k < CB; k++) {
        float a = row[k];
#pragma unroll
        for (int c = 0; c < 16; c++) row[CB + c] -= a * Bl[k * 16 + c];
      }
    }
  }
  __syncthreads();
  if (r >= CB && r < CB + 16) {
    int c = r - CB;
#pragma unroll
    for (int j = 0; j < 16; j++) {
      float dv = __shfl(row[CB + j], CB + j, 64);
      float ds = sqrtf(dv);
      float di = 1.0f / ds;
      if (c == j) row[CB + j] = ds;
      else if (c > j) row[CB + j] *= di;
#pragma unroll
      for (int c2 = j + 1; c2 < 16; c2++) {
        float lc2 = __shfl(row[CB + j], CB + c2, 64);
        if (c >= c2) row[CB + c2] -= row[CB + j] * lc2;
      }
    }
#pragma unroll
    for (int j = 0; j < 16; j++) Dg[c * 16 + j] = row[CB + j];
    Dinv[c] = 1.0f / row[CB + c];
  }
  __syncthreads();
  if (actv && r >= CB + 16) {
#pragma unroll
    for (int c2 = 0; c2 < 16; c2++) {
      float v = row[CB + c2];
#pragma unroll
      for (int k = 0; k < c2; k++) v -= row[CB + k] * Dg[c2 * 16 + k];
      row[CB + c2] = v * Dinv[c2];
    }
  }
  __syncthreads();
}

__global__ __launch_bounds__(768) void chol_panel(float* __restrict__ Lb, int jb) {
  int p = blockIdx.x;
  float* L = Lb + (size_t)p * 589824;
  int R = 768 - jb;
  int r = threadIdx.x;
  bool actv = r < R;
  __shared__ float Bl[48 * 16];
  __shared__ float Dg[256];
  __shared__ float Dinv[16];
  float row[64];
  float* my = L + (size_t)(jb + r) * 768 + jb;
  if (actv) {
#pragma unroll
    for (int i = 0; i < 16; i++) {
      f4v v = *(const f4v*)(my + 4 * i);
      row[4 * i] = v[0]; row[4 * i + 1] = v[1]; row[4 * i + 2] = v[2]; row[4 * i + 3] = v[3];
    }
  }
  chol_sub<0>(row, r, actv, Bl, Dg, Dinv);
  chol_sub<16>(row, r, actv, Bl, Dg, Dinv);
  chol_sub<32>(row, r, actv, Bl, Dg, Dinv);
  chol_sub<48>(row, r, actv, Bl, Dg, Dinv);
  if (actv) {
#pragma unroll
    for (int i = 0; i < 16; i++) {
      f4v v; v[0] = row[4 * i]; v[1] = row[4 * i + 1]; v[2] = row[4 * i + 2]; v[3] = row[4 * i + 3];
      *(f4v*)(my + 4 * i) = v;
    }
  }
}

// ---------------- L -> Ut (Ut[k][j] = L[j][k] if j>k else 0) + diag ---------
__global__ __launch_bounds__(256) void ltrans_k(const float* __restrict__ Lb,
                                                float* __restrict__ Ut,
                                                float* __restrict__ dg) {
  int p = blockIdx.z;
  const float* L = Lb + (size_t)p * 589824;
  float* U = Ut + (size_t)p * 589824;
  int r0 = blockIdx.x << 5, c0 = blockIdx.y << 5;
  __shared__ float t[32][33];
  int a = threadIdx.x >> 3, b4 = (threadIdx.x & 7) << 2;
  f4v v = *(const f4v*)(L + (size_t)(r0 + a) * 768 + c0 + b4);
  t[a][b4] = v[0]; t[a][b4 + 1] = v[1]; t[a][b4 + 2] = v[2]; t[a][b4 + 3] = v[3];
  __syncthreads();
  int k = c0 + a;
  f4v ov;
#pragma unroll
  for (int i = 0; i < 4; i++) {
    int j = r0 + b4 + i;
    float val = t[b4 + i][a];
    ov[i] = (j > k) ? val : 0.0f;
    if (j == k) dg[p * 768 + k] = val;
  }
  *(f4v*)(U + (size_t)k * 768 + r0 + b4) = ov;
}

// ---------------- column-sweep trsm + logp: 1 wave per (b,p) ----------------
__global__ __launch_bounds__(64) void trsm2(const float* __restrict__ Ut,
                                            const float* __restrict__ dg,
                                            const float* __restrict__ q,
                                            const float* __restrict__ mean,
                                            float* __restrict__ logp) {
  int gw = blockIdx.x;
  int p = gw >> 4, b = gw & 15;
  const float* U = Ut + (size_t)p * 589824;
  int lane = threadIdx.x;

  float y[12], dinv[12];
  float lacc = 0.0f;
#pragma unroll
  for (int m = 0; m < 12; m++) {
    int i = lane + (m << 6);
    y[m] = q[b * 768 + i] - mean[p * 768 + i];
    float d = dg[p * 768 + i];
    dinv[m] = 1.0f / d;
    lacc += __logf(d);
  }

  float u[4][12];
#pragma unroll
  for (int d0 = 0; d0 < 4; d0++)
#pragma unroll
    for (int mm = 0; mm < 12; mm++)
      u[d0][mm] = U[(size_t)d0 * 768 + lane + (mm << 6)];

#pragma unroll
  for (int m = 0; m < 12; m++) {
    for (int kb = 0; kb < 64; kb += 4) {
#pragma unroll
      for (int kd = 0; kd < 4; kd++) {
        int k = (m << 6) + kb + kd;
        float yo = __shfl(y[m], kb + kd, 64);
        float di = __shfl(dinv[m], kb + kd, 64);
        float yk = yo * di;
        if (lane == kb + kd) y[m] = yk;
        // prefetch row k+4 (overwrites slot kd after its use below)
        float un[12];
        bool pf = (k + 4) < 768;
        const float* rp = U + (size_t)(k + 4) * 768 + lane;
#pragma unroll
        for (int mm = 0; mm < 12; mm++) un[mm] = pf ? rp[mm << 6] : 0.0f;
#pragma unroll
        for (int mm = 0; mm < 12; mm++) y[mm] -= u[kd][mm] * yk;
#pragma unroll
        for (int mm = 0; mm < 12; mm++) u[kd][mm] = un[mm];
      }
    }
  }

  float quad = 0.0f;
#pragma unroll
  for (int m = 0; m < 12; m++) quad += y[m] * y[m];
  quad = wred64(quad);
  lacc = wred64(lacc);
  if (lane == 0)
    logp[b * 10 + p] = -0.5f * (768.0f * 1.8378770664093453f + 2.0f * lacc + quad);
}

__global__ void topk_k(const float* __restrict__ logp, int* __restrict__ tk) {
  int b = threadIdx.x;
  if (b >= 16) return;
  float v[10];
#pragma unroll
  for (int p = 0; p < 10; p++) v[p] = logp[b * 10 + p];
#pragma unroll
  for (int s = 0; s < 5; s++) {
    int bi = 0; float bv = v[0];
#pragma unroll
    for (int p = 1; p < 10; p++) if (v[p] > bv) { bv = v[p]; bi = p; }
    tk[b * 5 + s] = bi;
    v[bi] = -3.0e38f;
  }
}

DEV float blocksum256(float s, float* red) {
  s = wred64(s);
  __syncthreads();
  if ((threadIdx.x & 63) == 0) red[threadIdx.x >> 6] = s;
  __syncthreads();
  return red[0] + red[1] + red[2] + red[3];
}

__global__ __launch_bounds__(256) void final_head(const float* __restrict__ x,
                                                  const float* __restrict__ g,
                                                  const float* __restrict__ b,
                                                  const float* __restrict__ hw,
                                                  const float* __restrict__ hb,
                                                  float* __restrict__ out) {
  int bb = blockIdx.x, tid = threadIdx.x;
  __shared__ float xm[768];
  __shared__ float red[4];
  float a0 = 0, a1 = 0, a2 = 0;
  for (int j = 1; j <= 25; j++) {
    const float* rp = x + ((size_t)bb * 222 + j) * 768;
    float v0 = rp[tid], v1 = rp[tid + 256], v2 = rp[tid + 512];
    float s = blocksum256(v0 + v1 + v2, red);
    float mean = s * (1.0f / 768.0f);
    float d0 = v0 - mean, d1 = v1 - mean, d2 = v2 - mean;
    float s2 = blocksum256(d0 * d0 + d1 * d1 + d2 * d2, red);
    float rstd = rsqrtf(s2 * (1.0f / 768.0f) + 1e-6f);
    a0 += d0 * rstd * g[tid] + b[tid];
    a1 += d1 * rstd * g[tid + 256] + b[tid + 256];
    a2 += d2 * rstd * g[tid + 512] + b[tid + 512];
  }
  xm[tid] = a0 * (1.0f / 25.0f);
  xm[tid + 256] = a1 * (1.0f / 25.0f);
  xm[tid + 512] = a2 * (1.0f / 25.0f);
  __syncthreads();
  if (tid < 100) {
    float s = hb[tid];
    for (int d = 0; d < 768; d++) s += xm[d] * hw[d * 100 + tid];
    out[bb * 100 + tid] = s;
  }
}

// ---------------------------------------------------------------------------
extern "C" void kernel_launch(void* const* d_in, const int* in_sizes, int n_in,
                              void* d_out, int out_size, void* d_ws, size_t ws_size,
                              hipStream_t stream) {
  (void)in_sizes; (void)n_in; (void)out_size; (void)ws_size;
  const float* inp     = (const float*)d_in[0];
  const float* patchw  = (const float*)d_in[1];
  const float* patchb  = (const float*)d_in[2];
  const float* cls     = (const float*)d_in[3];
  const float* pos     = (const float*)d_in[4];
  const float* ln1g    = (const float*)d_in[5];
  const float* ln1b    = (const float*)d_in[6];
  const float* qkvw    = (const float*)d_in[7];
  const float* qkvb    = (const float*)d_in[8];
  const float* projw   = (const float*)d_in[9];
  const float* projb   = (const float*)d_in[10];
  const float* ln2g    = (const float*)d_in[11];
  const float* ln2b    = (const float*)d_in[12];
  const float* fc1w    = (const float*)d_in[13];
  const float* fc1b    = (const float*)d_in[14];
  const float* fc2w    = (const float*)d_in[15];
  const float* fc2b    = (const float*)d_in[16];
  const float* normg   = (const float*)d_in[17];
  const float* normb   = (const float*)d_in[18];
  const float* headw   = (const float*)d_in[19];
  const float* headb   = (const float*)d_in[20];
  const float* prompt  = (const float*)d_in[21];
  const float* meanp   = (const float*)d_in[22];
  const float* var     = (const float*)d_in[23];
  float* out = (float*)d_out;

  char* ws = (char*)d_ws;
  size_t cur = 0;
  auto alloc = [&](size_t bytes) { size_t r = cur; cur += (bytes + 255) & ~(size_t)255; return r; };
  float* x    = (float*)(ws + alloc((size_t)3552 * 768 * 4));
  float* img  = (float*)(ws + alloc((size_t)3136 * 768 * 4));
  float* qb   = (float*)(ws + alloc((size_t)16 * 768 * 4));
  float* logp = (float*)(ws + alloc(1024));
  int*   tk   = (int*)(ws + alloc(1024));
  float* dg   = (float*)(ws + alloc((size_t)10 * 768 * 4));
  h16_t* h16   = (h16_t*)(ws + alloc((size_t)3552 * 768 * 2));
  size_t qkv_off = alloc((size_t)3552 * 2304 * 2);
  h16_t* qkv16 = (h16_t*)(ws + qkv_off);
  size_t g_off = alloc((size_t)3552 * 3072 * 2);
  h16_t* g16   = (h16_t*)(ws + g_off);
  float* Lbuf  = (float*)(ws + alloc((size_t)10 * 589824 * 4));
  h16_t* wq16  = (h16_t*)(ws + alloc((size_t)12 * 2304 * 768 * 2));
  h16_t* wp16  = (h16_t*)(ws + alloc((size_t)12 * 768 * 768 * 2));
  h16_t* w116  = (h16_t*)(ws + alloc((size_t)12 * 3072 * 768 * 2));
  h16_t* w216  = (h16_t*)(ws + alloc((size_t)12 * 768 * 3072 * 2));
  h16_t* wpt16 = (h16_t*)(ws + alloc((size_t)768 * 768 * 2));
  // phase-disjoint aliases:
  h16_t* col16 = (h16_t*)(ws + g_off);   // im2col (before pass 1)
  float* Ut    = (float*)(ws + qkv_off); // 23.6 MB over qkv16+g16 (MVN phase)

  // -------- weight conversion / transposition (fp32 [K,N] -> fp16 [N,K])
  wcvt_t<<<dim3(72, 24, 12), 256, 0, stream>>>(qkvw, wq16, 768, 2304);
  wcvt_t<<<dim3(24, 24, 12), 256, 0, stream>>>(projw, wp16, 768, 768);
  wcvt_t<<<dim3(96, 24, 12), 256, 0, stream>>>(fc1w, w116, 768, 3072);
  wcvt_t<<<dim3(24, 96, 12), 256, 0, stream>>>(fc2w, w216, 3072, 768);
  cvt_flat<<<2304, 256, 0, stream>>>(patchw, wpt16, 589824);

  // -------- patch embed + x0
  im2col_k<<<9408, 256, 0, stream>>>(inp, col16);
  hgemm_t<2><<<dim3(25, 12), 256, 0, stream>>>(col16, wpt16, img, nullptr, patchb,
      3136, 768, 768, 768, 768, 768, 0, 1.0f, 0, 0);
  build_x0_k<<<9456, 256, 0, stream>>>(x, img, cls, pos);

  auto pass = [&](int Ntok) {
    int M = 16 * Ntok;
    int Mt = (M + 127) / 128;
    int Mt8 = (M + 255) / 256;
    int Qt = (Ntok + 63) / 64;
    for (int l = 0; l < 12; l++) {
      ln_rows<<<(M + 3) / 4, 256, 0, stream>>>(x, h16, nullptr, ln1g + l * 768, ln1b + l * 768, M, 768, 768);
      hgemm8<0><<<dim3(Mt8, 9), 512, 0, stream>>>(h16, wq16 + (size_t)l * 2304 * 768, qkv16,
          qkvb + l * 2304, M, 2304, 768, 2304);
      flash_attn<<<dim3(Qt, 192), 256, 0, stream>>>(qkv16, h16, Ntok);
      hgemm_t<2><<<dim3(Mt, 12), 256, 0, stream>>>(h16, wp16 + (size_t)l * 768 * 768, x, nullptr,
          projb + l * 768, M, 768, 768, 768, 768, 768, 0, 1.0f, 0, 1);
      ln_rows<<<(M + 3) / 4, 256, 0, stream>>>(x, h16, nullptr, ln2g + l * 768, ln2b + l * 768, M, 768, 768);
      hgemm8<1><<<dim3(Mt8, 12), 512, 0, stream>>>(h16, w116 + (size_t)l * 3072 * 768, g16,
          fc1b + l * 3072, M, 3072, 768, 3072);
      hgemm_t<2><<<dim3(Mt, 12), 256, 0, stream>>>(g16, w216 + (size_t)l * 768 * 3072, x, nullptr,
          fc2b + l * 768, M, 768, 3072, 3072, 3072, 768, 0, 1.0f, 0, 1);
    }
  };

  // -------- query pass, q = LN(x)[:,0]
  pass(197);
  ln_rows<<<4, 256, 0, stream>>>(x, nullptr, qb, normg, normb, 16, (long)197 * 768, 768);

  // -------- cov = |var| + I ; blocked Cholesky (NB=64) ; logp ; topk
  cov_init_k<<<23040, 256, 0, stream>>>(var, Lbuf);
  for (int m = 0; m < 12; m++) {
    int jb = 64 * m;
    if (m) sgemm_nt_chol<<<dim3((768 - jb) / 64, 1, 10), 256, 0, stream>>>(Lbuf, jb);
    chol_panel<<<10, 768, 0, stream>>>(Lbuf, jb);
  }
  ltrans_k<<<dim3(24, 24, 10), 256, 0, stream>>>(Lbuf, Ut, dg);
  trsm2<<<160, 64, 0, stream>>>(Ut, dg, qb, meanp, logp);
  topk_k<<<1, 64, 0, stream>>>(logp, tk);

  // -------- prompted pass + head
  build_x2_k<<<10656, 256, 0, stream>>>(x, img, cls, pos, prompt, tk);
  pass(222);
  final_head<<<16, 256, 0, stream>>>(x, normg, normb, headw, headb, out);
}

// Round 2
// 5356.379 us; speedup vs baseline: 1.2672x; 1.2256x over previous
//
#include <hip/hip_runtime.h>
#include <stdint.h>
#include <math.h>

// ---------------------------------------------------------------------------
// GausskeyL2P: ViT-B/16 x2 passes + MVN gaussian-key prompt selection.
// Round 5: occupancy-matched 8-phase GEMM variants.
//   qkv  -> hgemm8n  128x256 (225/252 blocks vs 117/126 at 256^2)
//   fc2/proj/patch -> hgemm128 128x128, 3-buffer rotation, vmcnt(4)
//   fc1  -> hgemm8 256^2 (unchanged, proven)
// All use counted-vmcnt pipelines (no vmcnt(0) drain in K-loop), T2 XOR
// swizzle, T5 setprio. hgemm_t kept (uninstantiated) as fallback reference.
// ---------------------------------------------------------------------------

typedef _Float16 h16_t;
typedef _Float16 h8v __attribute__((ext_vector_type(8)));
typedef _Float16 h4v __attribute__((ext_vector_type(4)));
typedef float    f4v __attribute__((ext_vector_type(4)));

#define DEV static __device__ __forceinline__

DEV float wred64(float s) {
#pragma unroll
  for (int m = 1; m < 64; m <<= 1) s += __shfl_xor(s, m, 64);
  return s;
}
DEV float gelu_f(float x) {  // jax.nn.gelu approximate=True (tanh form)
  float u = 0.7978845608028654f * x * (1.0f + 0.044715f * x * x);
  u = fminf(fmaxf(u, -30.0f), 30.0f);
  float e = __expf(-2.0f * u);
  return 0.5f * x * (1.0f + (1.0f - e) / (1.0f + e));
}

#define GLD16(gp, lp) __builtin_amdgcn_global_load_lds( \
  (const __attribute__((address_space(1))) unsigned int*)(const void*)(gp), \
  (__attribute__((address_space(3))) unsigned int*)(void*)(lp), 16, 0, 0)

// ---------------------------------------------------------------------------
// Legacy fp16 MFMA GEMM (single-buffered 2-barrier). Kept as template-only
// fallback; no instantiations remain.
// ---------------------------------------------------------------------------
template <int TJ>
__global__ __launch_bounds__(256) void hgemm_t(
    const h16_t* __restrict__ A, const h16_t* __restrict__ B,
    float* __restrict__ C32, h16_t* __restrict__ C16,
    const float* __restrict__ bias,
    int M, int N, int K, int lda, int ldb, int ldc32, int ldc16,
    float alpha, int act, int addC)
{
  constexpr int BN = TJ * 32;
  __shared__ __align__(16) h16_t As[128 * 32];
  __shared__ __align__(16) h16_t Bs[BN * 32];
  int tid = threadIdx.x;
  int w = tid >> 6, lane = tid & 63;
  int m0 = blockIdx.x << 7, n0 = blockIdx.y * BN;
  int qm = (w & 1) << 6, qn = (w >> 1) * (TJ * 16);
  int scol = (lane & 3) << 3;
  int fr = lane & 15, fk = (lane >> 4) << 3;

  f4v acc[4][TJ];
#pragma unroll
  for (int i = 0; i < 4; i++)
#pragma unroll
    for (int j = 0; j < TJ; j++)
#pragma unroll
      for (int r = 0; r < 4; r++) acc[i][j][r] = 0.0f;

  for (int k0 = 0; k0 < K; k0 += 32) {
    __syncthreads();
#pragma unroll
    for (int i = 0; i < 2; i++) {
      int rr = (w << 5) + (i << 4) + (lane >> 2);
      int gm = m0 + rr; gm = gm < M ? gm : M - 1;
      GLD16(A + (size_t)gm * lda + k0 + scol, &As[((w << 5) + (i << 4)) << 5]);
    }
#pragma unroll
    for (int i = 0; i < TJ / 2; i++) {
      int rb = w * (TJ / 2) * 16 + i * 16;
      int rr = rb + (lane >> 2);
      int gn = n0 + rr; gn = gn < N ? gn : N - 1;
      GLD16(B + (size_t)gn * ldb + k0 + scol, &Bs[rb << 5]);
    }
    __syncthreads();
    h8v af[4], bf[TJ];
#pragma unroll
    for (int t = 0; t < 4; t++)
      af[t] = *(const h8v*)&As[((qm + (t << 4) + fr) << 5) + fk];
#pragma unroll
    for (int t = 0; t < TJ; t++)
      bf[t] = *(const h8v*)&Bs[((qn + (t << 4) + fr) << 5) + fk];
#pragma unroll
    for (int ti = 0; ti < 4; ti++)
#pragma unroll
      for (int tj = 0; tj < TJ; tj++)
        acc[ti][tj] = __builtin_amdgcn_mfma_f32_16x16x32_f16(af[ti], bf[tj], acc[ti][tj], 0, 0, 0);
  }

  int colb = n0 + qn + fr;
  int rowb = m0 + qm + ((lane >> 4) << 2);
#pragma unroll
  for (int tj = 0; tj < TJ; tj++) {
    int col = colb + (tj << 4);
    if (col >= N) continue;
    float bv = (bias != nullptr) ? bias[col] : 0.0f;
#pragma unroll
    for (int ti = 0; ti < 4; ti++) {
#pragma unroll
      for (int rg = 0; rg < 4; rg++) {
        int row = rowb + (ti << 4) + rg;
        if (row >= M) continue;
        float v = alpha * acc[ti][tj][rg] + bv;
        if (act) v = gelu_f(v);
        if (C32) {
          size_t off = (size_t)row * ldc32 + col;
          if (addC) v += C32[off];
          C32[off] = v;
        }
        if (C16) C16[(size_t)row * ldc16 + col] = (h16_t)v;
      }
    }
  }
}

// ---------------------------------------------------------------------------
// Shared staging helper: R x (512 thr x 16 B) = R x 8 KiB of [rows][32k] fp16
// half-K panels. LDS dest linear (wave base + lane*16); global source
// pre-swizzled with the involution P ^= ((P>>7)&3)<<4 so swizzled ds_reads
// recover the data. Clamped row for M-tails.
// ---------------------------------------------------------------------------
template <int R>
DEV void stgN(const h16_t* __restrict__ src, int row0, int rowmax, int ldk,
              char* ldsb, unsigned lbase, int tid) {
#pragma unroll
  for (int r = 0; r < R; r++) {
    unsigned P = ((unsigned)r << 13) + ((unsigned)tid << 4);
    unsigned Q = P ^ (((P >> 7) & 3u) << 4);
    int row = (int)(Q >> 6);
    int kb = (int)((Q & 63u) >> 1);
    int gr = row0 + row; gr = gr < rowmax ? gr : rowmax - 1;
    GLD16(src + (size_t)gr * ldk + kb,
          ldsb + lbase + (r << 13) + ((tid >> 6) << 10));
  }
}

#define FENCE() asm volatile("" ::: "memory")
#define RBAR() do { FENCE(); __builtin_amdgcn_s_barrier(); FENCE(); } while (0)
#define VMW(N) asm volatile("s_waitcnt vmcnt(" #N ")" ::: "memory")

// ---------------------------------------------------------------------------
// 256x256 8-phase fp16 GEMM (fc1): C16 = act(A*B^T + bias). N%256==0, K%64==0.
// 512 thr (2Mx4N waves), 128 KiB dbuf LDS, vmcnt(8). Proven in R4.
// ---------------------------------------------------------------------------
#define LOADFRAGS(S, G) do { \
  unsigned ab_ = cb + ((unsigned)(S) << 14); \
  unsigned bb_ = cb + 32768u + ((unsigned)(S) << 14); \
  _Pragma("unroll") for (int t = 0; t < 4; t++) { \
    unsigned PA_ = ((unsigned)((wm << 7) + ((G) << 6) + (t << 4) + fr) << 6) + ((unsigned)quad << 4); \
    PA_ ^= ((PA_ >> 7) & 3u) << 4; \
    af[t] = *(const h8v*)(ldsb + ab_ + PA_); \
    unsigned PB_ = ((unsigned)((wn << 6) + (t << 4) + fr) << 6) + ((unsigned)quad << 4); \
    PB_ ^= ((PB_ >> 7) & 3u) << 4; \
    bf[t] = *(const h8v*)(ldsb + bb_ + PB_); \
  } } while (0)

#define MM8(G) do { \
  __builtin_amdgcn_s_setprio(1); \
  _Pragma("unroll") for (int ti = 0; ti < 4; ti++) \
  _Pragma("unroll") for (int tj = 0; tj < 4; tj++) \
    acc[((G) << 2) + ti][tj] = __builtin_amdgcn_mfma_f32_16x16x32_f16(af[ti], bf[tj], acc[((G) << 2) + ti][tj], 0, 0, 0); \
  __builtin_amdgcn_s_setprio(0); } while (0)

template <int ACT>
__global__ __launch_bounds__(512, 2) void hgemm8(
    const h16_t* __restrict__ A, const h16_t* __restrict__ B,
    h16_t* __restrict__ C16, const float* __restrict__ bias,
    int M, int N, int K, int ldc16)
{
  __shared__ __align__(16) char ldsb[131072];
  int tid = threadIdx.x;
  int w = tid >> 6, lane = tid & 63;
  int wm = w >> 2, wn = w & 3;
  int fr = lane & 15, quad = lane >> 4;
  int m0 = blockIdx.x << 8, n0 = blockIdx.y << 8;

  f4v acc[8][4];
#pragma unroll
  for (int i2 = 0; i2 < 8; i2++)
#pragma unroll
    for (int j2 = 0; j2 < 4; j2++)
#pragma unroll
      for (int r2 = 0; r2 < 4; r2++) acc[i2][j2][r2] = 0.0f;

  int NT = K >> 6;

  stgN<2>(A,      m0, M, K, ldsb, 0u,              tid);   // A(0,kh0)
  stgN<2>(B,      n0, N, K, ldsb, 32768u,          tid);   // B(0,kh0)
  stgN<2>(A + 32, m0, M, K, ldsb, 16384u,          tid);   // A(0,kh1)
  stgN<2>(B + 32, n0, N, K, ldsb, 32768u + 16384u, tid);   // B(0,kh1)
  stgN<2>(A + 64, m0, M, K, ldsb, 65536u,          tid);   // A(1,kh0)
  stgN<2>(B + 64, n0, N, K, ldsb, 65536u + 32768u, tid);   // B(1,kh0)
  VMW(8);
  __builtin_amdgcn_s_barrier();
  FENCE();

  for (int i = 0; i < NT; i++) {
    unsigned cb = (unsigned)(i & 1) << 16;
    unsigned ob = cb ^ 65536u;
    int tA = (i + 1 < NT) ? i + 1 : NT - 1;
    int tB = (i + 2 < NT) ? i + 2 : NT - 1;
    h8v af[4], bf[4];

    LOADFRAGS(0, 0);
    stgN<2>(A + (tA << 6) + 32, m0, M, K, ldsb, ob + 16384u, tid);
    RBAR();
    MM8(0);
    RBAR();
    LOADFRAGS(0, 1);
    stgN<2>(B + (tA << 6) + 32, n0, N, K, ldsb, ob + 49152u, tid);
    RBAR();
    MM8(1);
    VMW(8);
    RBAR();
    LOADFRAGS(1, 0);
    stgN<2>(A + (tB << 6), m0, M, K, ldsb, cb, tid);
    RBAR();
    MM8(0);
    RBAR();
    LOADFRAGS(1, 1);
    stgN<2>(B + (tB << 6), n0, N, K, ldsb, cb + 32768u, tid);
    RBAR();
    MM8(1);
    VMW(8);
    RBAR();
  }
  asm volatile("s_waitcnt vmcnt(0)" ::: "memory");

  int row0 = m0 + (wm << 7) + (quad << 2);
  int col0 = n0 + (wn << 6) + fr;
  float bv[4];
#pragma unroll
  for (int nj = 0; nj < 4; nj++) bv[nj] = bias[col0 + (nj << 4)];
#pragma unroll
  for (int mi = 0; mi < 8; mi++) {
#pragma unroll
    for (int rg = 0; rg < 4; rg++) {
      int row = row0 + (mi << 4) + rg;
      if (row < M) {
#pragma unroll
        for (int nj = 0; nj < 4; nj++) {
          float v = acc[mi][nj][rg] + bv[nj];
          if (ACT) v = gelu_f(v);
          C16[(size_t)row * ldc16 + col0 + (nj << 4)] = (h16_t)v;
        }
      }
    }
  }
}

// ---------------------------------------------------------------------------
// 128x256 2-phase-per-Ktile fp16 GEMM (qkv): C16 = A*B^T + bias.
// 512 thr, 8 waves 2Mx4N (wave tile 64x64 -> 16 MFMA/phase). LDS 96 KiB:
// per buffer (stride 49152): A kh at +kh*8192 (8K), B kh at +16384+kh*16384.
// Stage groups are 3 GLD (A=1, B=2); steady-state vmcnt(6) keeps the two
// newest groups in flight. Schedule per iter i (tile i in buf[i&1]):
//   ph1: frags(kh0) | stage (i+1,kh1)->ob | BAR | 16 MFMA | vmcnt(6) | BAR
//   ph2: frags(kh1) | stage (i+2,kh0)->cb | BAR | 16 MFMA | vmcnt(6) | BAR
// Barrier-separation: every stage targets a region whose frag reads were
// consumed by MFMAs before the preceding end-barrier. Clamped-tail restages
// keep vmcnt counts uniform and only ever land in never-again-read regions.
// ---------------------------------------------------------------------------
__global__ __launch_bounds__(512, 2) void hgemm8n(
    const h16_t* __restrict__ A, const h16_t* __restrict__ B,
    h16_t* __restrict__ C16, const float* __restrict__ bias,
    int M, int N, int K, int ldc16)
{
  __shared__ __align__(16) char ldsb[98304];
  int tid = threadIdx.x;
  int w = tid >> 6, lane = tid & 63;
  int wm = w >> 2, wn = w & 3;
  int fr = lane & 15, quad = lane >> 4;
  int m0 = blockIdx.x << 7, n0 = blockIdx.y << 8;

  f4v acc[4][4];
#pragma unroll
  for (int i2 = 0; i2 < 4; i2++)
#pragma unroll
    for (int j2 = 0; j2 < 4; j2++)
#pragma unroll
      for (int r2 = 0; r2 < 4; r2++) acc[i2][j2][r2] = 0.0f;

  int NT = K >> 6;

  // prologue: tile0 (kh0,kh1) -> buf0; tile1 kh0 -> buf1
  stgN<1>(A,      m0, M, K, ldsb, 0u,               tid);  // A(0,kh0)
  stgN<2>(B,      n0, N, K, ldsb, 16384u,           tid);  // B(0,kh0)
  stgN<1>(A + 32, m0, M, K, ldsb, 8192u,            tid);  // A(0,kh1)
  stgN<2>(B + 32, n0, N, K, ldsb, 32768u,           tid);  // B(0,kh1)
  stgN<1>(A + 64, m0, M, K, ldsb, 49152u,           tid);  // A(1,kh0)
  stgN<2>(B + 64, n0, N, K, ldsb, 49152u + 16384u,  tid);  // B(1,kh0)
  VMW(6);                     // (0,kh0) landed
  __builtin_amdgcn_s_barrier();
  FENCE();

  for (int i = 0; i < NT; i++) {
    unsigned cb = (i & 1) ? 49152u : 0u;
    unsigned ob = cb ^ 49152u;
    int tA = (i + 1 < NT) ? i + 1 : NT - 1;
    int tB = (i + 2 < NT) ? i + 2 : NT - 1;
    h8v af[4], bf[4];

    // ---- phase 1: kh0
#pragma unroll
    for (int t = 0; t < 4; t++) {
      unsigned PA = ((unsigned)((wm << 6) + (t << 4) + fr) << 6) + ((unsigned)quad << 4);
      PA ^= ((PA >> 7) & 3u) << 4;
      af[t] = *(const h8v*)(ldsb + cb + PA);
      unsigned PB = ((unsigned)((wn << 6) + (t << 4) + fr) << 6) + ((unsigned)quad << 4);
      PB ^= ((PB >> 7) & 3u) << 4;
      bf[t] = *(const h8v*)(ldsb + cb + 16384u + PB);
    }
    stgN<1>(A + (tA << 6) + 32, m0, M, K, ldsb, ob + 8192u,  tid);
    stgN<2>(B + (tA << 6) + 32, n0, N, K, ldsb, ob + 32768u, tid);
    RBAR();
    __builtin_amdgcn_s_setprio(1);
#pragma unroll
    for (int ti = 0; ti < 4; ti++)
#pragma unroll
      for (int tj = 0; tj < 4; tj++)
        acc[ti][tj] = __builtin_amdgcn_mfma_f32_16x16x32_f16(af[ti], bf[tj], acc[ti][tj], 0, 0, 0);
    __builtin_amdgcn_s_setprio(0);
    VMW(6);   // (i,kh1) landed (read in ph2)
    RBAR();

    // ---- phase 2: kh1
#pragma unroll
    for (int t = 0; t < 4; t++) {
      unsigned PA = ((unsigned)((wm << 6) + (t << 4) + fr) << 6) + ((unsigned)quad << 4);
      PA ^= ((PA >> 7) & 3u) << 4;
      af[t] = *(const h8v*)(ldsb + cb + 8192u + PA);
      unsigned PB = ((unsigned)((wn << 6) + (t << 4) + fr) << 6) + ((unsigned)quad << 4);
      PB ^= ((PB >> 7) & 3u) << 4;
      bf[t] = *(const h8v*)(ldsb + cb + 32768u + PB);
    }
    stgN<1>(A + (tB << 6), m0, M, K, ldsb, cb,           tid);
    stgN<2>(B + (tB << 6), n0, N, K, ldsb, cb + 16384u,  tid);
    RBAR();
    __builtin_amdgcn_s_setprio(1);
#pragma unroll
    for (int ti = 0; ti < 4; ti++)
#pragma unroll
      for (int tj = 0; tj < 4; tj++)
        acc[ti][tj] = __builtin_amdgcn_mfma_f32_16x16x32_f16(af[ti], bf[tj], acc[ti][tj], 0, 0, 0);
    __builtin_amdgcn_s_setprio(0);
    VMW(6);   // (i+1,kh0) landed (read next iter ph1)
    RBAR();
  }
  asm volatile("s_waitcnt vmcnt(0)" ::: "memory");

  int row0 = m0 + (wm << 6) + (quad << 2);
  int col0 = n0 + (wn << 6) + fr;
  float bv[4];
#pragma unroll
  for (int nj = 0; nj < 4; nj++) bv[nj] = bias[col0 + (nj << 4)];
#pragma unroll
  for (int mi = 0; mi < 4; mi++) {
#pragma unroll
    for (int rg = 0; rg < 4; rg++) {
      int row = row0 + (mi << 4) + rg;
      if (row < M) {
#pragma unroll
        for (int nj = 0; nj < 4; nj++) {
          float v = acc[mi][nj][rg] + bv[nj];
          C16[(size_t)row * ldc16 + col0 + (nj << 4)] = (h16_t)v;
        }
      }
    }
  }
}

// ---------------------------------------------------------------------------
// 128x128 1-phase-per-Ktile fp16 GEMM (proj/fc2/patch):
//   C32 = A*B^T + bias [+ C32]. N%128==0, K%64==0, K>=128. lda = ldb = K.
// 512 thr, 8 waves 2Mx4N (wave tile 64x32 -> 16 MFMA/Ktile). LDS 96 KiB =
// THREE 32 KiB buffers (rotation): iter i reads buf[i%3], stages tile i+2
// into buf[(i+2)%3] -- read and write sets always disjoint, so stages can be
// issued in the same phase as the frag reads. 4 GLD/iter -> vmcnt(4) drains
// exactly tile i+1 at end of iter i. Per buffer: A kh at +kh*8192,
// B kh at +16384+kh*8192.
// ---------------------------------------------------------------------------
__global__ __launch_bounds__(512, 2) void hgemm128(
    const h16_t* __restrict__ A, const h16_t* __restrict__ B,
    float* __restrict__ C32, const float* __restrict__ bias,
    int M, int N, int K, int ldc, int addC)
{
  __shared__ __align__(16) char ldsb[98304];
  int tid = threadIdx.x;
  int w = tid >> 6, lane = tid & 63;
  int wm = w >> 2, wn = w & 3;
  int fr = lane & 15, quad = lane >> 4;
  int m0 = blockIdx.x << 7, n0 = blockIdx.y << 7;

  f4v acc[4][2];
#pragma unroll
  for (int i2 = 0; i2 < 4; i2++)
#pragma unroll
    for (int j2 = 0; j2 < 2; j2++)
#pragma unroll
      for (int r2 = 0; r2 < 4; r2++) acc[i2][j2][r2] = 0.0f;

  int NT = K >> 6;

  // prologue: tile0 -> buf0, tile1 -> buf1 (4 GLD each)
  stgN<1>(A,       m0, M, K, ldsb, 0u,                tid);
  stgN<1>(A + 32,  m0, M, K, ldsb, 8192u,             tid);
  stgN<1>(B,       n0, N, K, ldsb, 16384u,            tid);
  stgN<1>(B + 32,  n0, N, K, ldsb, 24576u,            tid);
  stgN<1>(A + 64,  m0, M, K, ldsb, 32768u,            tid);
  stgN<1>(A + 96,  m0, M, K, ldsb, 32768u + 8192u,    tid);
  stgN<1>(B + 64,  n0, N, K, ldsb, 32768u + 16384u,   tid);
  stgN<1>(B + 96,  n0, N, K, ldsb, 32768u + 24576u,   tid);
  VMW(4);                     // tile0 landed
  __builtin_amdgcn_s_barrier();
  FENCE();

  unsigned cb = 0u;       // buffer holding tile i
  unsigned sb = 65536u;   // buffer receiving tile i+2
  for (int i = 0; i < NT; i++) {
    int tS = (i + 2 < NT) ? i + 2 : NT - 1;
    h8v af[2][4], bf[2][2];
#pragma unroll
    for (int kh = 0; kh < 2; kh++) {
      unsigned ab = cb + ((unsigned)kh << 13);
      unsigned bb = cb + 16384u + ((unsigned)kh << 13);
#pragma unroll
      for (int t = 0; t < 4; t++) {
        unsigned PA = ((unsigned)((wm << 6) + (t << 4) + fr) << 6) + ((unsigned)quad << 4);
        PA ^= ((PA >> 7) & 3u) << 4;
        af[kh][t] = *(const h8v*)(ldsb + ab + PA);
      }
#pragma unroll
      for (int t = 0; t < 2; t++) {
        unsigned PB = ((unsigned)((wn << 5) + (t << 4) + fr) << 6) + ((unsigned)quad << 4);
        PB ^= ((PB >> 7) & 3u) << 4;
        bf[kh][t] = *(const h8v*)(ldsb + bb + PB);
      }
    }
    stgN<1>(A + (tS << 6),      m0, M, K, ldsb, sb,           tid);
    stgN<1>(A + (tS << 6) + 32, m0, M, K, ldsb, sb + 8192u,   tid);
    stgN<1>(B + (tS << 6),      n0, N, K, ldsb, sb + 16384u,  tid);
    stgN<1>(B + (tS << 6) + 32, n0, N, K, ldsb, sb + 24576u,  tid);
    RBAR();
    __builtin_amdgcn_s_setprio(1);
#pragma unroll
    for (int kh = 0; kh < 2; kh++)
#pragma unroll
      for (int ti = 0; ti < 4; ti++)
#pragma unroll
        for (int tj = 0; tj < 2; tj++)
          acc[ti][tj] = __builtin_amdgcn_mfma_f32_16x16x32_f16(af[kh][ti], bf[kh][tj], acc[ti][tj], 0, 0, 0);
    __builtin_amdgcn_s_setprio(0);
    VMW(4);   // tile i+1 landed
    RBAR();
    cb = (cb == 65536u) ? 0u : cb + 32768u;
    sb = (sb == 65536u) ? 0u : sb + 32768u;
  }
  asm volatile("s_waitcnt vmcnt(0)" ::: "memory");

  int row0 = m0 + (wm << 6) + (quad << 2);
  int col0 = n0 + (wn << 5) + fr;
  float bv[2];
#pragma unroll
  for (int nj = 0; nj < 2; nj++) bv[nj] = bias[col0 + (nj << 4)];
#pragma unroll
  for (int mi = 0; mi < 4; mi++) {
#pragma unroll
    for (int rg = 0; rg < 4; rg++) {
      int row = row0 + (mi << 4) + rg;
      if (row < M) {
#pragma unroll
        for (int nj = 0; nj < 2; nj++) {
          size_t off = (size_t)row * ldc + col0 + (nj << 4);
          float v = acc[mi][nj][rg] + bv[nj];
          if (addC) v += C32[off];
          C32[off] = v;
        }
      }
    }
  }
}

// ---------------------------------------------------------------------------
// Fused flash attention: qkv16 [B*N, 2304] fp16 (bias applied) -> o [B*N,768]
// grid (ceil(N/64), B*12), 256 thr.
// ---------------------------------------------------------------------------
__global__ __launch_bounds__(256) void flash_attn(
    const h16_t* __restrict__ qkv, h16_t* __restrict__ o, int N)
{
  int z = blockIdx.y;
  int b = z / 12, h = z - (z / 12) * 12;
  const h16_t* base = qkv + (size_t)b * N * 2304 + h * 64;
  int q0 = blockIdx.x << 6;
  int tid = threadIdx.x, w = tid >> 6, lane = tid & 63;
  int fr = lane & 15, fk = (lane >> 4) << 3;
  int quad = lane >> 4;

  __shared__ __align__(16) h16_t Qs[2][64 * 32];
  __shared__ __align__(16) h16_t Ks[2][64 * 32];
  __shared__ __align__(16) h16_t Ps[4][1024];
  __shared__ __align__(16) h16_t Vt[64 * 68];

#pragma unroll
  for (int s = 0; s < 2; s++) {
    int gq = q0 + (w << 4) + (lane >> 2); gq = gq < N ? gq : N - 1;
    GLD16(base + (size_t)gq * 2304 + (s << 5) + ((lane & 3) << 3), &Qs[s][(w << 4) << 5]);
  }
  __syncthreads();
  h8v af0 = *(const h8v*)&Qs[0][(((w << 4) + fr) << 5) + fk];
  h8v af1 = *(const h8v*)&Qs[1][(((w << 4) + fr) << 5) + fk];

  float mrow[4], lrow[4];
  f4v accO[4];
#pragma unroll
  for (int r = 0; r < 4; r++) { mrow[r] = -1e30f; lrow[r] = 0.0f; }
#pragma unroll
  for (int t = 0; t < 4; t++)
#pragma unroll
    for (int r = 0; r < 4; r++) accO[t][r] = 0.0f;

  int nj = (N + 63) >> 6;
  for (int jt = 0; jt < nj; jt++) {
    int j0 = jt << 6;
    __syncthreads();
#pragma unroll
    for (int s = 0; s < 2; s++) {
      int gj = j0 + (w << 4) + (lane >> 2); gj = gj < N ? gj : N - 1;
      GLD16(base + (size_t)gj * 2304 + 768 + (s << 5) + ((lane & 3) << 3), &Ks[s][(w << 4) << 5]);
    }
#pragma unroll
    for (int i = 0; i < 16; i++) {
      int j = (w << 4) + i;
      int gj = j0 + j; gj = gj < N ? gj : N - 1;
      Vt[lane * 68 + j] = base[(size_t)gj * 2304 + 1536 + lane];
    }
    __syncthreads();

    f4v s4[4];
#pragma unroll
    for (int t = 0; t < 4; t++) {
      h8v b0 = *(const h8v*)&Ks[0][(((t << 4) + fr) << 5) + fk];
      h8v b1 = *(const h8v*)&Ks[1][(((t << 4) + fr) << 5) + fk];
      f4v s; s[0] = s[1] = s[2] = s[3] = 0.0f;
      s = __builtin_amdgcn_mfma_f32_16x16x32_f16(af0, b0, s, 0, 0, 0);
      s = __builtin_amdgcn_mfma_f32_16x16x32_f16(af1, b1, s, 0, 0, 0);
      s4[t] = s;
    }
#pragma unroll
    for (int r = 0; r < 4; r++) {
      float tm = -1e30f;
#pragma unroll
      for (int t = 0; t < 4; t++) {
        float v = s4[t][r] * 0.125f;
        if (j0 + (t << 4) + fr >= N) v = -1e30f;
        s4[t][r] = v;
        tm = fmaxf(tm, v);
      }
#pragma unroll
      for (int m = 1; m < 16; m <<= 1) tm = fmaxf(tm, __shfl_xor(tm, m, 64));
      float mn = fmaxf(mrow[r], tm);
      float alpha = __expf(mrow[r] - mn);
      mrow[r] = mn;
      float rs = 0.0f;
#pragma unroll
      for (int t = 0; t < 4; t++) {
        float e = __expf(s4[t][r] - mn);
        s4[t][r] = e;
        rs += e;
      }
#pragma unroll
      for (int m = 1; m < 16; m <<= 1) rs += __shfl_xor(rs, m, 64);
      lrow[r] = lrow[r] * alpha + rs;
#pragma unroll
      for (int t = 0; t < 4; t++) accO[t][r] *= alpha;
#pragma unroll
      for (int t = 0; t < 4; t++)
        Ps[w][((t >> 1) << 9) + (((quad << 2) + r) << 5) + ((t & 1) << 4) + fr] = (h16_t)s4[t][r];
    }
#pragma unroll
    for (int s = 0; s < 2; s++) {
      h8v ap = *(const h8v*)&Ps[w][(s << 9) + (fr << 5) + fk];
#pragma unroll
      for (int t = 0; t < 4; t++) {
        int vidx = ((t << 4) + fr) * 68 + (s << 5) + fk;
        h4v v0 = *(const h4v*)&Vt[vidx];
        h4v v1 = *(const h4v*)&Vt[vidx + 4];
        h8v bv;
#pragma unroll
        for (int i = 0; i < 4; i++) { bv[i] = v0[i]; bv[i + 4] = v1[i]; }
        accO[t] = __builtin_amdgcn_mfma_f32_16x16x32_f16(ap, bv, accO[t], 0, 0, 0);
      }
    }
  }

#pragma unroll
  for (int r = 0; r < 4; r++) {
    int q = q0 + (w << 4) + (quad << 2) + r;
    if (q >= N) continue;
    float inv = 1.0f / lrow[r];
    h16_t* op = o + ((size_t)b * N + q) * 768 + h * 64 + fr;
#pragma unroll
    for (int t = 0; t < 4; t++) op[t << 4] = (h16_t)(accO[t][r] * inv);
  }
}

// ---------------- weight convert: fp32 [K,N] -> fp16 [N,K] (batched z) ------
__global__ __launch_bounds__(256) void wcvt_t(const float* __restrict__ in,
                                              h16_t* __restrict__ o, int K, int N) {
  int z = blockIdx.z;
  in += (size_t)z * K * N;
  o  += (size_t)z * K * N;
  int n0 = blockIdx.x << 5, k0 = blockIdx.y << 5;
  __shared__ float t[32][33];
  int a = threadIdx.x >> 3, b4 = (threadIdx.x & 7) << 2;
  f4v v = *(const f4v*)(in + (size_t)(k0 + a) * N + n0 + b4);
  t[a][b4] = v[0]; t[a][b4 + 1] = v[1]; t[a][b4 + 2] = v[2]; t[a][b4 + 3] = v[3];
  __syncthreads();
  h4v h;
#pragma unroll
  for (int i = 0; i < 4; i++) h[i] = (h16_t)t[b4 + i][a];
  *(h4v*)(o + (size_t)(n0 + a) * K + k0 + b4) = h;
}

__global__ void cvt_flat(const float* __restrict__ in, h16_t* __restrict__ o, int n) {
  int i = blockIdx.x * 256 + threadIdx.x;
  if (i < n) o[i] = (h16_t)in[i];
}

// ---------------- patch embed im2col (fp16 out) -----------------------------
__global__ void im2col_k(const float* __restrict__ in, h16_t* __restrict__ col) {
  int idx = blockIdx.x * 256 + threadIdx.x;
  if (idx >= 16 * 196 * 768) return;
  int k = idx % 768; int t = idx / 768; int p2 = t % 196; int b = t / 196;
  int c = k >> 8, ij = k & 255, i = ij >> 4, j = ij & 15;
  int py = p2 / 14, px = p2 % 14;
  col[idx] = (h16_t)in[(((size_t)b * 3 + c) * 224 + py * 16 + i) * 224 + px * 16 + j];
}

__global__ void build_x0_k(float* __restrict__ x, const float* __restrict__ img,
                           const float* __restrict__ cls, const float* __restrict__ pos) {
  int idx = blockIdx.x * 256 + threadIdx.x;
  if (idx >= 16 * 197 * 768) return;
  int d = idx % 768; int t = idx / 768; int n = t % 197; int b = t / 197;
  float v = (n == 0) ? cls[d] : img[((size_t)b * 196 + (n - 1)) * 768 + d];
  x[idx] = v + pos[n * 768 + d];
}

__global__ void build_x2_k(float* __restrict__ x, const float* __restrict__ img,
                           const float* __restrict__ cls, const float* __restrict__ pos,
                           const float* __restrict__ prompt, const int* __restrict__ tk) {
  int idx = blockIdx.x * 256 + threadIdx.x;
  if (idx >= 16 * 222 * 768) return;
  int d = idx % 768; int t = idx / 768; int n = t % 222; int b = t / 222;
  float v;
  if (n == 0) v = cls[d] + pos[d];
  else if (n < 26) {
    int s = (n - 1) / 5, li = (n - 1) % 5;
    v = prompt[((size_t)tk[b * 5 + s] * 5 + li) * 768 + d] + pos[d];
  } else {
    v = img[((size_t)b * 196 + (n - 26)) * 768 + d];
  }
  x[idx] = v;
}

// ---------------- LayerNorm rows (wave per row), fp16 and/or fp32 out -------
__global__ void ln_rows(const float* __restrict__ in, h16_t* __restrict__ o16,
                        float* __restrict__ o32, const float* __restrict__ g,
                        const float* __restrict__ b, int rows, long istr, long ostr) {
  int gw = ((blockIdx.x << 8) + threadIdx.x) >> 6;
  int lane = threadIdx.x & 63;
  if (gw >= rows) return;
  const float* rp = in + (size_t)gw * istr;
  float v[12]; float s = 0;
#pragma unroll
  for (int i = 0; i < 12; i++) { v[i] = rp[lane + (i << 6)]; s += v[i]; }
  s = wred64(s);
  float mean = s * (1.0f / 768.0f);
  float s2 = 0;
#pragma unroll
  for (int i = 0; i < 12; i++) { float d = v[i] - mean; s2 += d * d; }
  s2 = wred64(s2);
  float rstd = rsqrtf(s2 * (1.0f / 768.0f) + 1e-6f);
#pragma unroll
  for (int i = 0; i < 12; i++) {
    int k = lane + (i << 6);
    float o = (v[i] - mean) * rstd * g[k] + b[k];
    if (o16) o16[(size_t)gw * ostr + k] = (h16_t)o;
    if (o32) o32[(size_t)gw * ostr + k] = o;
  }
}

// ---------------- Cholesky: cov init, NT update GEMM, panel factor ----------
__global__ void cov_init_k(const float* __restrict__ var, float* __restrict__ Lb) {
  size_t i = (size_t)blockIdx.x * 256 + threadIdx.x;
  if (i >= (size_t)10 * 589824) return;
  int ij = (int)(i % 589824);
  int r = ij / 768, c = ij - r * 768;
  Lb[i] = fabsf(var[i]) + ((r == c) ? 1.0f : 0.0f);
}

__global__ __launch_bounds__(256) void sgemm_nt_chol(float* __restrict__ Lb, int jb) {
  int p = blockIdx.z;
  float* base = Lb + (size_t)p * 589824;
  const float* A = base + (size_t)jb * 768;
  const float* Bp = A;
  float* C = base + (size_t)jb * 768 + jb;
  int m0 = blockIdx.x << 6;
  __shared__ float As[16][64];
  __shared__ float Bs[16][64];
  int tid = threadIdx.x;
  int am = tid & 63, ak = (tid >> 6) << 2;
  int tm = (tid >> 4) << 2, tn = (tid & 15) << 2;
  float acc[4][4] = {};
  for (int k0 = 0; k0 < jb; k0 += 16) {
    f4v va = *(const f4v*)(A + (size_t)(m0 + am) * 768 + k0 + ak);
    f4v vb = *(const f4v*)(Bp + (size_t)am * 768 + k0 + ak);
#pragma unroll
    for (int i = 0; i < 4; i++) { As[ak + i][am] = va[i]; Bs[ak + i][am] = vb[i]; }
    __syncthreads();
#pragma unroll
    for (int kk = 0; kk < 16; kk++) {
      f4v a = *(const f4v*)&As[kk][tm];
      f4v b = *(const f4v*)&Bs[kk][tn];
#pragma unroll
      for (int i = 0; i < 4; i++)
#pragma unroll
        for (int j = 0; j < 4; j++) acc[i][j] += a[i] * b[j];
    }
    __syncthreads();
  }
#pragma unroll
  for (int i = 0; i < 4; i++)
#pragma unroll
    for (int j = 0; j < 4; j++)
      C[(size_t)(m0 + tm + i) * 768 + tn + j] -= acc[i][j];
}

template <int CB>
DEV void chol_sub(float (&row)[64], int r, bool actv, float* Bl, float* Dg, float* Dinv) {
  if constexpr (CB > 0) {
    if (actv && r >= CB && r < CB + 16) {
      int c = r - CB;
#pragma unroll
      for (int k = 0; k < CB; k++) Bl[k * 16 + c] = row[k];
    }
    __syncthreads();
    if (actv && r >= CB) {
#pragma unroll
      for (int k = 0; k < CB; k++) {
        float a = row[k];
#pragma unroll
        for (int c = 0; c < 16; c++) row[CB + c] -= a * Bl[k * 16 + c];
      }
    }
  }
  __syncthreads();
  if (r >= CB && r < CB + 16) {
    int c = r - CB;
#pragma unroll
    for (int j = 0; j < 16; j++) {
      float dv = __shfl(row[CB + j], CB + j, 64);
      float ds = sqrtf(dv);
      float di = 1.0f / ds;
      if (c == j) row[CB + j] = ds;
      else if (c > j) row[CB + j] *= di;
#pragma unroll
      for (int c2 = j + 1; c2 < 16; c2++) {
        float lc2 = __shfl(row[CB + j], CB + c2, 64);
        if (c >= c2) row[CB + c2] -= row[CB + j] * lc2;
      }
    }
#pragma unroll
    for (int j = 0; j < 16; j++) Dg[c * 16 + j] = row[CB + j];
    Dinv[c] = 1.0f / row[CB + c];
  }
  __syncthreads();
  if (actv && r >= CB + 16) {
#pragma unroll
    for (int c2 = 0; c2 < 16; c2++) {
      float v = row[CB + c2];
#pragma unroll
      for (int k = 0; k < c2; k++) v -= row[CB + k] * Dg[c2 * 16 + k];
      row[CB + c2] = v * Dinv[c2];
    }
  }
  __syncthreads();
}

__global__ __launch_bounds__(768) void chol_panel(float* __restrict__ Lb, int jb) {
  int p = blockIdx.x;
  float* L = Lb + (size_t)p * 589824;
  int R = 768 - jb;
  int r = threadIdx.x;
  bool actv = r < R;
  __shared__ float Bl[48 * 16];
  __shared__ float Dg[256];
  __shared__ float Dinv[16];
  float row[64];
  float* my = L + (size_t)(jb + r) * 768 + jb;
  if (actv) {
#pragma unroll
    for (int i = 0; i < 16; i++) {
      f4v v = *(const f4v*)(my + 4 * i);
      row[4 * i] = v[0]; row[4 * i + 1] = v[1]; row[4 * i + 2] = v[2]; row[4 * i + 3] = v[3];
    }
  }
  chol_sub<0>(row, r, actv, Bl, Dg, Dinv);
  chol_sub<16>(row, r, actv, Bl, Dg, Dinv);
  chol_sub<32>(row, r, actv, Bl, Dg, Dinv);
  chol_sub<48>(row, r, actv, Bl, Dg, Dinv);
  if (actv) {
#pragma unroll
    for (int i = 0; i < 16; i++) {
      f4v v; v[0] = row[4 * i]; v[1] = row[4 * i + 1]; v[2] = row[4 * i + 2]; v[3] = row[4 * i + 3];
      *(f4v*)(my + 4 * i) = v;
    }
  }
}

// ---------------- L -> Ut (Ut[k][j] = L[j][k] if j>k else 0) + diag ---------
__global__ __launch_bounds__(256) void ltrans_k(const float* __restrict__ Lb,
                                                float* __restrict__ Ut,
                                                float* __restrict__ dg) {
  int p = blockIdx.z;
  const float* L = Lb + (size_t)p * 589824;
  float* U = Ut + (size_t)p * 589824;
  int r0 = blockIdx.x << 5, c0 = blockIdx.y << 5;
  __shared__ float t[32][33];
  int a = threadIdx.x >> 3, b4 = (threadIdx.x & 7) << 2;
  f4v v = *(const f4v*)(L + (size_t)(r0 + a) * 768 + c0 + b4);
  t[a][b4] = v[0]; t[a][b4 + 1] = v[1]; t[a][b4 + 2] = v[2]; t[a][b4 + 3] = v[3];
  __syncthreads();
  int k = c0 + a;
  f4v ov;
#pragma unroll
  for (int i = 0; i < 4; i++) {
    int j = r0 + b4 + i;
    float val = t[b4 + i][a];
    ov[i] = (j > k) ? val : 0.0f;
    if (j == k) dg[p * 768 + k] = val;
  }
  *(f4v*)(U + (size_t)k * 768 + r0 + b4) = ov;
}

// ---------------- column-sweep trsm + logp: 1 wave per (b,p) ----------------
__global__ __launch_bounds__(64) void trsm2(const float* __restrict__ Ut,
                                            const float* __restrict__ dg,
                                            const float* __restrict__ q,
                                            const float* __restrict__ mean,
                                            float* __restrict__ logp) {
  int gw = blockIdx.x;
  int p = gw >> 4, b = gw & 15;
  const float* U = Ut + (size_t)p * 589824;
  int lane = threadIdx.x;

  float y[12], dinv[12];
  float lacc = 0.0f;
#pragma unroll
  for (int m = 0; m < 12; m++) {
    int i = lane + (m << 6);
    y[m] = q[b * 768 + i] - mean[p * 768 + i];
    float d = dg[p * 768 + i];
    dinv[m] = 1.0f / d;
    lacc += __logf(d);
  }

  float u[4][12];
#pragma unroll
  for (int d0 = 0; d0 < 4; d0++)
#pragma unroll
    for (int mm = 0; mm < 12; mm++)
      u[d0][mm] = U[(size_t)d0 * 768 + lane + (mm << 6)];

#pragma unroll
  for (int m = 0; m < 12; m++) {
    for (int kb = 0; kb < 64; kb += 4) {
#pragma unroll
      for (int kd = 0; kd < 4; kd++) {
        int k = (m << 6) + kb + kd;
        float yo = __shfl(y[m], kb + kd, 64);
        float di = __shfl(dinv[m], kb + kd, 64);
        float yk = yo * di;
        if (lane == kb + kd) y[m] = yk;
        // prefetch row k+4 (overwrites slot kd after its use below)
        float un[12];
        bool pf = (k + 4) < 768;
        const float* rp = U + (size_t)(k + 4) * 768 + lane;
#pragma unroll
        for (int mm = 0; mm < 12; mm++) un[mm] = pf ? rp[mm << 6] : 0.0f;
#pragma unroll
        for (int mm = 0; mm < 12; mm++) y[mm] -= u[kd][mm] * yk;
#pragma unroll
        for (int mm = 0; mm < 12; mm++) u[kd][mm] = un[mm];
      }
    }
  }

  float quad = 0.0f;
#pragma unroll
  for (int m = 0; m < 12; m++) quad += y[m] * y[m];
  quad = wred64(quad);
  lacc = wred64(lacc);
  if (lane == 0)
    logp[b * 10 + p] = -0.5f * (768.0f * 1.8378770664093453f + 2.0f * lacc + quad);
}

__global__ void topk_k(const float* __restrict__ logp, int* __restrict__ tk) {
  int b = threadIdx.x;
  if (b >= 16) return;
  float v[10];
#pragma unroll
  for (int p = 0; p < 10; p++) v[p] = logp[b * 10 + p];
#pragma unroll
  for (int s = 0; s < 5; s++) {
    int bi = 0; float bv = v[0];
#pragma unroll
    for (int p = 1; p < 10; p++) if (v[p] > bv) { bv = v[p]; bi = p; }
    tk[b * 5 + s] = bi;
    v[bi] = -3.0e38f;
  }
}

DEV float blocksum256(float s, float* red) {
  s = wred64(s);
  __syncthreads();
  if ((threadIdx.x & 63) == 0) red[threadIdx.x >> 6] = s;
  __syncthreads();
  return red[0] + red[1] + red[2] + red[3];
}

__global__ __launch_bounds__(256) void final_head(const float* __restrict__ x,
                                                  const float* __restrict__ g,
                                                  const float* __restrict__ b,
                                                  const float* __restrict__ hw,
                                                  const float* __restrict__ hb,
                                                  float* __restrict__ out) {
  int bb = blockIdx.x, tid = threadIdx.x;
  __shared__ float xm[768];
  __shared__ float red[4];
  float a0 = 0, a1 = 0, a2 = 0;
  for (int j = 1; j <= 25; j++) {
    const float* rp = x + ((size_t)bb * 222 + j) * 768;
    float v0 = rp[tid], v1 = rp[tid + 256], v2 = rp[tid + 512];
    float s = blocksum256(v0 + v1 + v2, red);
    float mean = s * (1.0f / 768.0f);
    float d0 = v0 - mean, d1 = v1 - mean, d2 = v2 - mean;
    float s2 = blocksum256(d0 * d0 + d1 * d1 + d2 * d2, red);
    float rstd = rsqrtf(s2 * (1.0f / 768.0f) + 1e-6f);
    a0 += d0 * rstd * g[tid] + b[tid];
    a1 += d1 * rstd * g[tid + 256] + b[tid + 256];
    a2 += d2 * rstd * g[tid + 512] + b[tid + 512];
  }
  xm[tid] = a0 * (1.0f / 25.0f);
  xm[tid + 256] = a1 * (1.0f / 25.0f);
  xm[tid + 512] = a2 * (1.0f / 25.0f);
  __syncthreads();
  if (tid < 100) {
    float s = hb[tid];
    for (int d = 0; d < 768; d++) s += xm[d] * hw[d * 100 + tid];
    out[bb * 100 + tid] = s;
  }
}

// ---------------------------------------------------------------------------
extern "C" void kernel_launch(void* const* d_in, const int* in_sizes, int n_in,
                              void* d_out, int out_size, void* d_ws, size_t ws_size,
                              hipStream_t stream) {
  (void)in_sizes; (void)n_in; (void)out_size; (void)ws_size;
  const float* inp     = (const float*)d_in[0];
  const float* patchw  = (const float*)d_in[1];
  const float* patchb  = (const float*)d_in[2];
  const float* cls     = (const float*)d_in[3];
  const float* pos     = (const float*)d_in[4];
  const float* ln1g    = (const float*)d_in[5];
  const float* ln1b    = (const float*)d_in[6];
  const float* qkvw    = (const float*)d_in[7];
  const float* qkvb    = (const float*)d_in[8];
  const float* projw   = (const float*)d_in[9];
  const float* projb   = (const float*)d_in[10];
  const float* ln2g    = (const float*)d_in[11];
  const float* ln2b    = (const float*)d_in[12];
  const float* fc1w    = (const float*)d_in[13];
  const float* fc1b    = (const float*)d_in[14];
  const float* fc2w    = (const float*)d_in[15];
  const float* fc2b    = (const float*)d_in[16];
  const float* normg   = (const float*)d_in[17];
  const float* normb   = (const float*)d_in[18];
  const float* headw   = (const float*)d_in[19];
  const float* headb   = (const float*)d_in[20];
  const float* prompt  = (const float*)d_in[21];
  const float* meanp   = (const float*)d_in[22];
  const float* var     = (const float*)d_in[23];
  float* out = (float*)d_out;

  char* ws = (char*)d_ws;
  size_t cur = 0;
  auto alloc = [&](size_t bytes) { size_t r = cur; cur += (bytes + 255) & ~(size_t)255; return r; };
  float* x    = (float*)(ws + alloc((size_t)3552 * 768 * 4));
  float* img  = (float*)(ws + alloc((size_t)3136 * 768 * 4));
  float* qb   = (float*)(ws + alloc((size_t)16 * 768 * 4));
  float* logp = (float*)(ws + alloc(1024));
  int*   tk   = (int*)(ws + alloc(1024));
  float* dg   = (float*)(ws + alloc((size_t)10 * 768 * 4));
  h16_t* h16   = (h16_t*)(ws + alloc((size_t)3552 * 768 * 2));
  size_t qkv_off = alloc((size_t)3552 * 2304 * 2);
  h16_t* qkv16 = (h16_t*)(ws + qkv_off);
  size_t g_off = alloc((size_t)3552 * 3072 * 2);
  h16_t* g16   = (h16_t*)(ws + g_off);
  float* Lbuf  = (float*)(ws + alloc((size_t)10 * 589824 * 4));
  h16_t* wq16  = (h16_t*)(ws + alloc((size_t)12 * 2304 * 768 * 2));
  h16_t* wp16  = (h16_t*)(ws + alloc((size_t)12 * 768 * 768 * 2));
  h16_t* w116  = (h16_t*)(ws + alloc((size_t)12 * 3072 * 768 * 2));
  h16_t* w216  = (h16_t*)(ws + alloc((size_t)12 * 768 * 3072 * 2));
  h16_t* wpt16 = (h16_t*)(ws + alloc((size_t)768 * 768 * 2));
  // phase-disjoint aliases:
  h16_t* col16 = (h16_t*)(ws + g_off);   // im2col (before pass 1)
  float* Ut    = (float*)(ws + qkv_off); // 23.6 MB over qkv16+g16 (MVN phase)

  // -------- weight conversion / transposition (fp32 [K,N] -> fp16 [N,K])
  wcvt_t<<<dim3(72, 24, 12), 256, 0, stream>>>(qkvw, wq16, 768, 2304);
  wcvt_t<<<dim3(24, 24, 12), 256, 0, stream>>>(projw, wp16, 768, 768);
  wcvt_t<<<dim3(96, 24, 12), 256, 0, stream>>>(fc1w, w116, 768, 3072);
  wcvt_t<<<dim3(24, 96, 12), 256, 0, stream>>>(fc2w, w216, 3072, 768);
  cvt_flat<<<2304, 256, 0, stream>>>(patchw, wpt16, 589824);

  // -------- patch embed + x0
  im2col_k<<<9408, 256, 0, stream>>>(inp, col16);
  hgemm128<<<dim3(25, 6), 512, 0, stream>>>(col16, wpt16, img, patchb,
      3136, 768, 768, 768, 0);
  build_x0_k<<<9456, 256, 0, stream>>>(x, img, cls, pos);

  auto pass = [&](int Ntok) {
    int M = 16 * Ntok;
    int Mt1 = (M + 127) / 128;
    int Mt8 = (M + 255) / 256;
    int Qt = (Ntok + 63) / 64;
    for (int l = 0; l < 12; l++) {
      ln_rows<<<(M + 3) / 4, 256, 0, stream>>>(x, h16, nullptr, ln1g + l * 768, ln1b + l * 768, M, 768, 768);
      hgemm8n<<<dim3(Mt1, 9), 512, 0, stream>>>(h16, wq16 + (size_t)l * 2304 * 768, qkv16,
          qkvb + l * 2304, M, 2304, 768, 2304);
      flash_attn<<<dim3(Qt, 192), 256, 0, stream>>>(qkv16, h16, Ntok);
      hgemm128<<<dim3(Mt1, 6), 512, 0, stream>>>(h16, wp16 + (size_t)l * 768 * 768, x,
          projb + l * 768, M, 768, 768, 768, 1);
      ln_rows<<<(M + 3) / 4, 256, 0, stream>>>(x, h16, nullptr, ln2g + l * 768, ln2b + l * 768, M, 768, 768);
      hgemm8<1><<<dim3(Mt8, 12), 512, 0, stream>>>(h16, w116 + (size_t)l * 3072 * 768, g16,
          fc1b + l * 3072, M, 3072, 768, 3072);
      hgemm128<<<dim3(Mt1, 6), 512, 0, stream>>>(g16, w216 + (size_t)l * 768 * 3072, x,
          fc2b + l * 768, M, 768, 3072, 768, 1);
    }
  };

  // -------- query pass, q = LN(x)[:,0]
  pass(197);
  ln_rows<<<4, 256, 0, stream>>>(x, nullptr, qb, normg, normb, 16, (long)197 * 768, 768);

  // -------- cov = |var| + I ; blocked Cholesky (NB=64) ; logp ; topk
  cov_init_k<<<23040, 256, 0, stream>>>(var, Lbuf);
  for (int m = 0; m < 12; m++) {
    int jb = 64 * m;
    if (m) sgemm_nt_chol<<<dim3((768 - jb) / 64, 1, 10), 256, 0, stream>>>(Lbuf, jb);
    chol_panel<<<10, 768, 0, stream>>>(Lbuf, jb);
  }
  ltrans_k<<<dim3(24, 24, 10), 256, 0, stream>>>(Lbuf, Ut, dg);
  trsm2<<<160, 64, 0, stream>>>(Ut, dg, qb, meanp, logp);
  topk_k<<<1, 64, 0, stream>>>(logp, tk);

  // -------- prompted pass + head
  build_x2_k<<<10656, 256, 0, stream>>>(x, img, cls, pos, prompt, tk);
  pass(222);
  final_head<<<16, 256, 0, stream>>>(x, normg, normb, headw, headb, out);
}

// Round 3
// 5332.930 us; speedup vs baseline: 1.2728x; 1.0044x over previous
//
#include <hip/hip_runtime.h>
#include <stdint.h>
#include <math.h>

// ---------------------------------------------------------------------------
// GausskeyL2P: ViT-B/16 x2 passes + MVN gaussian-key prompt selection.
// Round 6: unified single-barrier 3-buffer-rotation GEMMs.
//   hgemm_q 128x256 BK=64 (qkv)       : 3x48KB LDS, vmcnt(6), 1 bar/K-tile
//   hgemm_f 256x256 BK=32 (fc1)       : 3x32KB LDS, vmcnt(4), 1 bar/K-tile
//   hgemm_p 128x128 BK=64 (proj/fc2/patch): 3x32KB, vmcnt(4), 1 bar/K-tile
// Invariant: write-set buf[(i+2)%3] and read-set buf[i%3] disjoint; WAR safe
// via the phase i-1 end barrier; RAW safe via counted vmcnt at phase end.
// Accumulation order per C element unchanged (k ascending) -> bitwise-same.
// trsm2: register prefetch depth 4 -> 8.
// ---------------------------------------------------------------------------

typedef _Float16 h16_t;
typedef _Float16 h8v __attribute__((ext_vector_type(8)));
typedef _Float16 h4v __attribute__((ext_vector_type(4)));
typedef float    f4v __attribute__((ext_vector_type(4)));

#define DEV static __device__ __forceinline__

DEV float wred64(float s) {
#pragma unroll
  for (int m = 1; m < 64; m <<= 1) s += __shfl_xor(s, m, 64);
  return s;
}
DEV float gelu_f(float x) {  // jax.nn.gelu approximate=True (tanh form)
  float u = 0.7978845608028654f * x * (1.0f + 0.044715f * x * x);
  u = fminf(fmaxf(u, -30.0f), 30.0f);
  float e = __expf(-2.0f * u);
  return 0.5f * x * (1.0f + (1.0f - e) / (1.0f + e));
}

#define GLD16(gp, lp) __builtin_amdgcn_global_load_lds( \
  (const __attribute__((address_space(1))) unsigned int*)(const void*)(gp), \
  (__attribute__((address_space(3))) unsigned int*)(void*)(lp), 16, 0, 0)

// ---------------------------------------------------------------------------
// Staging: R x (512 thr x 16 B) = R x 8 KiB of [rows][32 k] fp16 half-K
// panels. LDS dest linear; global source pre-swizzled with involution
// P ^= ((P>>7)&3)<<4 so the swizzled ds_reads recover the data.
// ---------------------------------------------------------------------------
template <int R>
DEV void stgN(const h16_t* __restrict__ src, int row0, int rowmax, int ldk,
              char* ldsb, unsigned lbase, int tid) {
#pragma unroll
  for (int r = 0; r < R; r++) {
    unsigned P = ((unsigned)r << 13) + ((unsigned)tid << 4);
    unsigned Q = P ^ (((P >> 7) & 3u) << 4);
    int row = (int)(Q >> 6);
    int kb = (int)((Q & 63u) >> 1);
    int gr = row0 + row; gr = gr < rowmax ? gr : rowmax - 1;
    GLD16(src + (size_t)gr * ldk + kb,
          ldsb + lbase + (r << 13) + ((tid >> 6) << 10));
  }
}

#define FENCE() asm volatile("" ::: "memory")
#define RBAR() do { FENCE(); __builtin_amdgcn_s_barrier(); FENCE(); } while (0)
#define VMW(N) asm volatile("s_waitcnt vmcnt(" #N ")" ::: "memory")

// swizzled LDS frag read of row `row` (64B rows), k-quad `quad`, at region rb
DEV h8v frag_rd(const char* ldsb, unsigned rb, int row, int quad) {
  unsigned P = ((unsigned)row << 6) + ((unsigned)quad << 4);
  P ^= ((P >> 7) & 3u) << 4;
  return *(const h8v*)(ldsb + rb + P);
}

// ---------------------------------------------------------------------------
// hgemm_q: 128x256, BK=64, C16 = A*B^T + bias. N%256==0, K%64==0, K>=192.
// 512 thr, 8 waves 2Mx4N (wave 64x64). LDS 144 KiB = 3 x 48 KiB buffers:
// per buffer: A kh at +kh*8KB (16KB), B kh at +16KB + kh*16KB (32KB).
// 6 GLD per tile -> vmcnt(6).
// ---------------------------------------------------------------------------
__global__ __launch_bounds__(512, 2) void hgemm_q(
    const h16_t* __restrict__ A, const h16_t* __restrict__ B,
    h16_t* __restrict__ C16, const float* __restrict__ bias,
    int M, int N, int K, int ldc16)
{
  __shared__ __align__(16) char ldsb[147456];
  int tid = threadIdx.x;
  int w = tid >> 6, lane = tid & 63;
  int wm = w >> 2, wn = w & 3;
  int fr = lane & 15, quad = lane >> 4;
  int m0 = blockIdx.x << 7, n0 = blockIdx.y << 8;

  f4v acc[4][4];
#pragma unroll
  for (int i2 = 0; i2 < 4; i2++)
#pragma unroll
    for (int j2 = 0; j2 < 4; j2++)
#pragma unroll
      for (int r2 = 0; r2 < 4; r2++) acc[i2][j2][r2] = 0.0f;

  int NT = K >> 6;

  auto stage = [&](int t, unsigned bb) {
    stgN<1>(A + (t << 6),      m0, M, K, ldsb, bb,           tid);
    stgN<1>(A + (t << 6) + 32, m0, M, K, ldsb, bb + 8192u,   tid);
    stgN<2>(B + (t << 6),      n0, N, K, ldsb, bb + 16384u,  tid);
    stgN<2>(B + (t << 6) + 32, n0, N, K, ldsb, bb + 32768u,  tid);
  };
  stage(0, 0u);
  stage(1, 49152u);
  VMW(6);
  __builtin_amdgcn_s_barrier();
  FENCE();

  unsigned cb = 0u, sb = 98304u;
  for (int i = 0; i < NT; i++) {
    int tS = (i + 2 < NT) ? i + 2 : NT - 1;
    stage(tS, sb);
    h8v af[2][4], bf[2][4];
#pragma unroll
    for (int kh = 0; kh < 2; kh++)
#pragma unroll
      for (int t = 0; t < 4; t++) {
        af[kh][t] = frag_rd(ldsb, cb + ((unsigned)kh << 13),
                            (wm << 6) + (t << 4) + fr, quad);
        bf[kh][t] = frag_rd(ldsb, cb + 16384u + ((unsigned)kh << 14),
                            (wn << 6) + (t << 4) + fr, quad);
      }
    __builtin_amdgcn_s_setprio(1);
#pragma unroll
    for (int kh = 0; kh < 2; kh++)
#pragma unroll
      for (int ti = 0; ti < 4; ti++)
#pragma unroll
        for (int tj = 0; tj < 4; tj++)
          acc[ti][tj] = __builtin_amdgcn_mfma_f32_16x16x32_f16(af[kh][ti], bf[kh][tj], acc[ti][tj], 0, 0, 0);
    __builtin_amdgcn_s_setprio(0);
    VMW(6);
    RBAR();
    cb = (cb == 98304u) ? 0u : cb + 49152u;
    sb = (sb == 98304u) ? 0u : sb + 49152u;
  }
  asm volatile("s_waitcnt vmcnt(0)" ::: "memory");

  int row0 = m0 + (wm << 6) + (quad << 2);
  int col0 = n0 + (wn << 6) + fr;
  float bv[4];
#pragma unroll
  for (int nj = 0; nj < 4; nj++) bv[nj] = bias[col0 + (nj << 4)];
#pragma unroll
  for (int mi = 0; mi < 4; mi++) {
#pragma unroll
    for (int rg = 0; rg < 4; rg++) {
      int row = row0 + (mi << 4) + rg;
      if (row < M) {
#pragma unroll
        for (int nj = 0; nj < 4; nj++) {
          float v = acc[mi][nj][rg] + bv[nj];
          C16[(size_t)row * ldc16 + col0 + (nj << 4)] = (h16_t)v;
        }
      }
    }
  }
}

// ---------------------------------------------------------------------------
// hgemm_f: 256x256, BK=32, C16 = gelu(A*B^T + bias). N%256==0, K%32==0.
// 512 thr, 8 waves 2Mx4N (wave 128x64, ratio 2.67). LDS 96 KiB = 3 x 32 KiB:
// per buffer: A [256][32] at +0 (16KB), B [256][32] at +16KB.
// 4 GLD per tile -> vmcnt(4).
// ---------------------------------------------------------------------------
__global__ __launch_bounds__(512, 2) void hgemm_f(
    const h16_t* __restrict__ A, const h16_t* __restrict__ B,
    h16_t* __restrict__ C16, const float* __restrict__ bias,
    int M, int N, int K, int ldc16)
{
  __shared__ __align__(16) char ldsb[98304];
  int tid = threadIdx.x;
  int w = tid >> 6, lane = tid & 63;
  int wm = w >> 2, wn = w & 3;
  int fr = lane & 15, quad = lane >> 4;
  int m0 = blockIdx.x << 8, n0 = blockIdx.y << 8;

  f4v acc[8][4];
#pragma unroll
  for (int i2 = 0; i2 < 8; i2++)
#pragma unroll
    for (int j2 = 0; j2 < 4; j2++)
#pragma unroll
      for (int r2 = 0; r2 < 4; r2++) acc[i2][j2][r2] = 0.0f;

  int NT = K >> 5;

  auto stage = [&](int t, unsigned bb) {
    stgN<2>(A + (t << 5), m0, M, K, ldsb, bb,          tid);
    stgN<2>(B + (t << 5), n0, N, K, ldsb, bb + 16384u, tid);
  };
  stage(0, 0u);
  stage(1, 32768u);
  VMW(4);
  __builtin_amdgcn_s_barrier();
  FENCE();

  unsigned cb = 0u, sb = 65536u;
  for (int i = 0; i < NT; i++) {
    int tS = (i + 2 < NT) ? i + 2 : NT - 1;
    stage(tS, sb);
    h8v af[8], bf[4];
#pragma unroll
    for (int t = 0; t < 8; t++)
      af[t] = frag_rd(ldsb, cb, (wm << 7) + (t << 4) + fr, quad);
#pragma unroll
    for (int t = 0; t < 4; t++)
      bf[t] = frag_rd(ldsb, cb + 16384u, (wn << 6) + (t << 4) + fr, quad);
    __builtin_amdgcn_s_setprio(1);
#pragma unroll
    for (int ti = 0; ti < 8; ti++)
#pragma unroll
      for (int tj = 0; tj < 4; tj++)
        acc[ti][tj] = __builtin_amdgcn_mfma_f32_16x16x32_f16(af[ti], bf[tj], acc[ti][tj], 0, 0, 0);
    __builtin_amdgcn_s_setprio(0);
    VMW(4);
    RBAR();
    cb = (cb == 65536u) ? 0u : cb + 32768u;
    sb = (sb == 65536u) ? 0u : sb + 32768u;
  }
  asm volatile("s_waitcnt vmcnt(0)" ::: "memory");

  int row0 = m0 + (wm << 7) + (quad << 2);
  int col0 = n0 + (wn << 6) + fr;
  float bv[4];
#pragma unroll
  for (int nj = 0; nj < 4; nj++) bv[nj] = bias[col0 + (nj << 4)];
#pragma unroll
  for (int mi = 0; mi < 8; mi++) {
#pragma unroll
    for (int rg = 0; rg < 4; rg++) {
      int row = row0 + (mi << 4) + rg;
      if (row < M) {
#pragma unroll
        for (int nj = 0; nj < 4; nj++) {
          float v = gelu_f(acc[mi][nj][rg] + bv[nj]);
          C16[(size_t)row * ldc16 + col0 + (nj << 4)] = (h16_t)v;
        }
      }
    }
  }
}

// ---------------------------------------------------------------------------
// hgemm_p: 128x128, BK=64, C32 = A*B^T + bias [+C32]. N%128==0, K%64==0.
// 512 thr, 8 waves 2Mx4N (wave 64x32). LDS 96 KiB = 3 x 32 KiB:
// per buffer: A kh at +kh*8KB, B kh at +16KB + kh*8KB.
// 4 GLD per tile -> vmcnt(4).
// ---------------------------------------------------------------------------
__global__ __launch_bounds__(512, 2) void hgemm_p(
    const h16_t* __restrict__ A, const h16_t* __restrict__ B,
    float* __restrict__ C32, const float* __restrict__ bias,
    int M, int N, int K, int ldc, int addC)
{
  __shared__ __align__(16) char ldsb[98304];
  int tid = threadIdx.x;
  int w = tid >> 6, lane = tid & 63;
  int wm = w >> 2, wn = w & 3;
  int fr = lane & 15, quad = lane >> 4;
  int m0 = blockIdx.x << 7, n0 = blockIdx.y << 7;

  f4v acc[4][2];
#pragma unroll
  for (int i2 = 0; i2 < 4; i2++)
#pragma unroll
    for (int j2 = 0; j2 < 2; j2++)
#pragma unroll
      for (int r2 = 0; r2 < 4; r2++) acc[i2][j2][r2] = 0.0f;

  int NT = K >> 6;

  auto stage = [&](int t, unsigned bb) {
    stgN<1>(A + (t << 6),      m0, M, K, ldsb, bb,           tid);
    stgN<1>(A + (t << 6) + 32, m0, M, K, ldsb, bb + 8192u,   tid);
    stgN<1>(B + (t << 6),      n0, N, K, ldsb, bb + 16384u,  tid);
    stgN<1>(B + (t << 6) + 32, n0, N, K, ldsb, bb + 24576u,  tid);
  };
  stage(0, 0u);
  stage(1, 32768u);
  VMW(4);
  __builtin_amdgcn_s_barrier();
  FENCE();

  unsigned cb = 0u, sb = 65536u;
  for (int i = 0; i < NT; i++) {
    int tS = (i + 2 < NT) ? i + 2 : NT - 1;
    stage(tS, sb);
    h8v af[2][4], bf[2][2];
#pragma unroll
    for (int kh = 0; kh < 2; kh++) {
#pragma unroll
      for (int t = 0; t < 4; t++)
        af[kh][t] = frag_rd(ldsb, cb + ((unsigned)kh << 13),
                            (wm << 6) + (t << 4) + fr, quad);
#pragma unroll
      for (int t = 0; t < 2; t++)
        bf[kh][t] = frag_rd(ldsb, cb + 16384u + ((unsigned)kh << 13),
                            (wn << 5) + (t << 4) + fr, quad);
    }
    __builtin_amdgcn_s_setprio(1);
#pragma unroll
    for (int kh = 0; kh < 2; kh++)
#pragma unroll
      for (int ti = 0; ti < 4; ti++)
#pragma unroll
        for (int tj = 0; tj < 2; tj++)
          acc[ti][tj] = __builtin_amdgcn_mfma_f32_16x16x32_f16(af[kh][ti], bf[kh][tj], acc[ti][tj], 0, 0, 0);
    __builtin_amdgcn_s_setprio(0);
    VMW(4);
    RBAR();
    cb = (cb == 65536u) ? 0u : cb + 32768u;
    sb = (sb == 65536u) ? 0u : sb + 32768u;
  }
  asm volatile("s_waitcnt vmcnt(0)" ::: "memory");

  int row0 = m0 + (wm << 6) + (quad << 2);
  int col0 = n0 + (wn << 5) + fr;
  float bv[2];
#pragma unroll
  for (int nj = 0; nj < 2; nj++) bv[nj] = bias[col0 + (nj << 4)];
#pragma unroll
  for (int mi = 0; mi < 4; mi++) {
#pragma unroll
    for (int rg = 0; rg < 4; rg++) {
      int row = row0 + (mi << 4) + rg;
      if (row < M) {
#pragma unroll
        for (int nj = 0; nj < 2; nj++) {
          size_t off = (size_t)row * ldc + col0 + (nj << 4);
          float v = acc[mi][nj][rg] + bv[nj];
          if (addC) v += C32[off];
          C32[off] = v;
        }
      }
    }
  }
}

// ---------------------------------------------------------------------------
// Fused flash attention: qkv16 [B*N, 2304] fp16 (bias applied) -> o [B*N,768]
// grid (ceil(N/64), B*12), 256 thr.
// ---------------------------------------------------------------------------
__global__ __launch_bounds__(256) void flash_attn(
    const h16_t* __restrict__ qkv, h16_t* __restrict__ o, int N)
{
  int z = blockIdx.y;
  int b = z / 12, h = z - (z / 12) * 12;
  const h16_t* base = qkv + (size_t)b * N * 2304 + h * 64;
  int q0 = blockIdx.x << 6;
  int tid = threadIdx.x, w = tid >> 6, lane = tid & 63;
  int fr = lane & 15, fk = (lane >> 4) << 3;
  int quad = lane >> 4;

  __shared__ __align__(16) h16_t Qs[2][64 * 32];
  __shared__ __align__(16) h16_t Ks[2][64 * 32];
  __shared__ __align__(16) h16_t Ps[4][1024];
  __shared__ __align__(16) h16_t Vt[64 * 68];

#pragma unroll
  for (int s = 0; s < 2; s++) {
    int gq = q0 + (w << 4) + (lane >> 2); gq = gq < N ? gq : N - 1;
    GLD16(base + (size_t)gq * 2304 + (s << 5) + ((lane & 3) << 3), &Qs[s][(w << 4) << 5]);
  }
  __syncthreads();
  h8v af0 = *(const h8v*)&Qs[0][(((w << 4) + fr) << 5) + fk];
  h8v af1 = *(const h8v*)&Qs[1][(((w << 4) + fr) << 5) + fk];

  float mrow[4], lrow[4];
  f4v accO[4];
#pragma unroll
  for (int r = 0; r < 4; r++) { mrow[r] = -1e30f; lrow[r] = 0.0f; }
#pragma unroll
  for (int t = 0; t < 4; t++)
#pragma unroll
    for (int r = 0; r < 4; r++) accO[t][r] = 0.0f;

  int nj = (N + 63) >> 6;
  for (int jt = 0; jt < nj; jt++) {
    int j0 = jt << 6;
    __syncthreads();
#pragma unroll
    for (int s = 0; s < 2; s++) {
      int gj = j0 + (w << 4) + (lane >> 2); gj = gj < N ? gj : N - 1;
      GLD16(base + (size_t)gj * 2304 + 768 + (s << 5) + ((lane & 3) << 3), &Ks[s][(w << 4) << 5]);
    }
#pragma unroll
    for (int i = 0; i < 16; i++) {
      int j = (w << 4) + i;
      int gj = j0 + j; gj = gj < N ? gj : N - 1;
      Vt[lane * 68 + j] = base[(size_t)gj * 2304 + 1536 + lane];
    }
    __syncthreads();

    f4v s4[4];
#pragma unroll
    for (int t = 0; t < 4; t++) {
      h8v b0 = *(const h8v*)&Ks[0][(((t << 4) + fr) << 5) + fk];
      h8v b1 = *(const h8v*)&Ks[1][(((t << 4) + fr) << 5) + fk];
      f4v s; s[0] = s[1] = s[2] = s[3] = 0.0f;
      s = __builtin_amdgcn_mfma_f32_16x16x32_f16(af0, b0, s, 0, 0, 0);
      s = __builtin_amdgcn_mfma_f32_16x16x32_f16(af1, b1, s, 0, 0, 0);
      s4[t] = s;
    }
#pragma unroll
    for (int r = 0; r < 4; r++) {
      float tm = -1e30f;
#pragma unroll
      for (int t = 0; t < 4; t++) {
        float v = s4[t][r] * 0.125f;
        if (j0 + (t << 4) + fr >= N) v = -1e30f;
        s4[t][r] = v;
        tm = fmaxf(tm, v);
      }
#pragma unroll
      for (int m = 1; m < 16; m <<= 1) tm = fmaxf(tm, __shfl_xor(tm, m, 64));
      float mn = fmaxf(mrow[r], tm);
      float alpha = __expf(mrow[r] - mn);
      mrow[r] = mn;
      float rs = 0.0f;
#pragma unroll
      for (int t = 0; t < 4; t++) {
        float e = __expf(s4[t][r] - mn);
        s4[t][r] = e;
        rs += e;
      }
#pragma unroll
      for (int m = 1; m < 16; m <<= 1) rs += __shfl_xor(rs, m, 64);
      lrow[r] = lrow[r] * alpha + rs;
#pragma unroll
      for (int t = 0; t < 4; t++) accO[t][r] *= alpha;
#pragma unroll
      for (int t = 0; t < 4; t++)
        Ps[w][((t >> 1) << 9) + (((quad << 2) + r) << 5) + ((t & 1) << 4) + fr] = (h16_t)s4[t][r];
    }
#pragma unroll
    for (int s = 0; s < 2; s++) {
      h8v ap = *(const h8v*)&Ps[w][(s << 9) + (fr << 5) + fk];
#pragma unroll
      for (int t = 0; t < 4; t++) {
        int vidx = ((t << 4) + fr) * 68 + (s << 5) + fk;
        h4v v0 = *(const h4v*)&Vt[vidx];
        h4v v1 = *(const h4v*)&Vt[vidx + 4];
        h8v bv;
#pragma unroll
        for (int i = 0; i < 4; i++) { bv[i] = v0[i]; bv[i + 4] = v1[i]; }
        accO[t] = __builtin_amdgcn_mfma_f32_16x16x32_f16(ap, bv, accO[t], 0, 0, 0);
      }
    }
  }

#pragma unroll
  for (int r = 0; r < 4; r++) {
    int q = q0 + (w << 4) + (quad << 2) + r;
    if (q >= N) continue;
    float inv = 1.0f / lrow[r];
    h16_t* op = o + ((size_t)b * N + q) * 768 + h * 64 + fr;
#pragma unroll
    for (int t = 0; t < 4; t++) op[t << 4] = (h16_t)(accO[t][r] * inv);
  }
}

// ---------------- weight convert: fp32 [K,N] -> fp16 [N,K] (batched z) ------
__global__ __launch_bounds__(256) void wcvt_t(const float* __restrict__ in,
                                              h16_t* __restrict__ o, int K, int N) {
  int z = blockIdx.z;
  in += (size_t)z * K * N;
  o  += (size_t)z * K * N;
  int n0 = blockIdx.x << 5, k0 = blockIdx.y << 5;
  __shared__ float t[32][33];
  int a = threadIdx.x >> 3, b4 = (threadIdx.x & 7) << 2;
  f4v v = *(const f4v*)(in + (size_t)(k0 + a) * N + n0 + b4);
  t[a][b4] = v[0]; t[a][b4 + 1] = v[1]; t[a][b4 + 2] = v[2]; t[a][b4 + 3] = v[3];
  __syncthreads();
  h4v h;
#pragma unroll
  for (int i = 0; i < 4; i++) h[i] = (h16_t)t[b4 + i][a];
  *(h4v*)(o + (size_t)(n0 + a) * K + k0 + b4) = h;
}

__global__ void cvt_flat(const float* __restrict__ in, h16_t* __restrict__ o, int n) {
  int i = blockIdx.x * 256 + threadIdx.x;
  if (i < n) o[i] = (h16_t)in[i];
}

// ---------------- patch embed im2col (fp16 out) -----------------------------
__global__ void im2col_k(const float* __restrict__ in, h16_t* __restrict__ col) {
  int idx = blockIdx.x * 256 + threadIdx.x;
  if (idx >= 16 * 196 * 768) return;
  int k = idx % 768; int t = idx / 768; int p2 = t % 196; int b = t / 196;
  int c = k >> 8, ij = k & 255, i = ij >> 4, j = ij & 15;
  int py = p2 / 14, px = p2 % 14;
  col[idx] = (h16_t)in[(((size_t)b * 3 + c) * 224 + py * 16 + i) * 224 + px * 16 + j];
}

__global__ void build_x0_k(float* __restrict__ x, const float* __restrict__ img,
                           const float* __restrict__ cls, const float* __restrict__ pos) {
  int idx = blockIdx.x * 256 + threadIdx.x;
  if (idx >= 16 * 197 * 768) return;
  int d = idx % 768; int t = idx / 768; int n = t % 197; int b = t / 197;
  float v = (n == 0) ? cls[d] : img[((size_t)b * 196 + (n - 1)) * 768 + d];
  x[idx] = v + pos[n * 768 + d];
}

__global__ void build_x2_k(float* __restrict__ x, const float* __restrict__ img,
                           const float* __restrict__ cls, const float* __restrict__ pos,
                           const float* __restrict__ prompt, const int* __restrict__ tk) {
  int idx = blockIdx.x * 256 + threadIdx.x;
  if (idx >= 16 * 222 * 768) return;
  int d = idx % 768; int t = idx / 768; int n = t % 222; int b = t / 222;
  float v;
  if (n == 0) v = cls[d] + pos[d];
  else if (n < 26) {
    int s = (n - 1) / 5, li = (n - 1) % 5;
    v = prompt[((size_t)tk[b * 5 + s] * 5 + li) * 768 + d] + pos[d];
  } else {
    v = img[((size_t)b * 196 + (n - 26)) * 768 + d];
  }
  x[idx] = v;
}

// ---------------- LayerNorm rows (wave per row), fp16 and/or fp32 out -------
__global__ void ln_rows(const float* __restrict__ in, h16_t* __restrict__ o16,
                        float* __restrict__ o32, const float* __restrict__ g,
                        const float* __restrict__ b, int rows, long istr, long ostr) {
  int gw = ((blockIdx.x << 8) + threadIdx.x) >> 6;
  int lane = threadIdx.x & 63;
  if (gw >= rows) return;
  const float* rp = in + (size_t)gw * istr;
  float v[12]; float s = 0;
#pragma unroll
  for (int i = 0; i < 12; i++) { v[i] = rp[lane + (i << 6)]; s += v[i]; }
  s = wred64(s);
  float mean = s * (1.0f / 768.0f);
  float s2 = 0;
#pragma unroll
  for (int i = 0; i < 12; i++) { float d = v[i] - mean; s2 += d * d; }
  s2 = wred64(s2);
  float rstd = rsqrtf(s2 * (1.0f / 768.0f) + 1e-6f);
#pragma unroll
  for (int i = 0; i < 12; i++) {
    int k = lane + (i << 6);
    float o = (v[i] - mean) * rstd * g[k] + b[k];
    if (o16) o16[(size_t)gw * ostr + k] = (h16_t)o;
    if (o32) o32[(size_t)gw * ostr + k] = o;
  }
}

// ---------------- Cholesky: cov init, NT update GEMM, panel factor ----------
__global__ void cov_init_k(const float* __restrict__ var, float* __restrict__ Lb) {
  size_t i = (size_t)blockIdx.x * 256 + threadIdx.x;
  if (i >= (size_t)10 * 589824) return;
  int ij = (int)(i % 589824);
  int r = ij / 768, c = ij - r * 768;
  Lb[i] = fabsf(var[i]) + ((r == c) ? 1.0f : 0.0f);
}

__global__ __launch_bounds__(256) void sgemm_nt_chol(float* __restrict__ Lb, int jb) {
  int p = blockIdx.z;
  float* base = Lb + (size_t)p * 589824;
  const float* A = base + (size_t)jb * 768;
  const float* Bp = A;
  float* C = base + (size_t)jb * 768 + jb;
  int m0 = blockIdx.x << 6;
  __shared__ float As[16][64];
  __shared__ float Bs[16][64];
  int tid = threadIdx.x;
  int am = tid & 63, ak = (tid >> 6) << 2;
  int tm = (tid >> 4) << 2, tn = (tid & 15) << 2;
  float acc[4][4] = {};
  for (int k0 = 0; k0 < jb; k0 += 16) {
    f4v va = *(const f4v*)(A + (size_t)(m0 + am) * 768 + k0 + ak);
    f4v vb = *(const f4v*)(Bp + (size_t)am * 768 + k0 + ak);
#pragma unroll
    for (int i = 0; i < 4; i++) { As[ak + i][am] = va[i]; Bs[ak + i][am] = vb[i]; }
    __syncthreads();
#pragma unroll
    for (int kk = 0; kk < 16; kk++) {
      f4v a = *(const f4v*)&As[kk][tm];
      f4v b = *(const f4v*)&Bs[kk][tn];
#pragma unroll
      for (int i = 0; i < 4; i++)
#pragma unroll
        for (int j = 0; j < 4; j++) acc[i][j] += a[i] * b[j];
    }
    __syncthreads();
  }
#pragma unroll
  for (int i = 0; i < 4; i++)
#pragma unroll
    for (int j = 0; j < 4; j++)
      C[(size_t)(m0 + tm + i) * 768 + tn + j] -= acc[i][j];
}

template <int CB>
DEV void chol_sub(float (&row)[64], int r, bool actv, float* Bl, float* Dg, float* Dinv) {
  if constexpr (CB > 0) {
    if (actv && r >= CB && r < CB + 16) {
      int c = r - CB;
#pragma unroll
      for (int k = 0; k < CB; k++) Bl[k * 16 + c] = row[k];
    }
    __syncthreads();
    if (actv && r >= CB) {
#pragma unroll
      for (int k = 0; k < CB; k++) {
        float a = row[k];
#pragma unroll
        for (int c = 0; c < 16; c++) row[CB + c] -= a * Bl[k * 16 + c];
      }
    }
  }
  __syncthreads();
  if (r >= CB && r < CB + 16) {
    int c = r - CB;
#pragma unroll
    for (int j = 0; j < 16; j++) {
      float dv = __shfl(row[CB + j], CB + j, 64);
      float ds = sqrtf(dv);
      float di = 1.0f / ds;
      if (c == j) row[CB + j] = ds;
      else if (c > j) row[CB + j] *= di;
#pragma unroll
      for (int c2 = j + 1; c2 < 16; c2++) {
        float lc2 = __shfl(row[CB + j], CB + c2, 64);
        if (c >= c2) row[CB + c2] -= row[CB + j] * lc2;
      }
    }
#pragma unroll
    for (int j = 0; j < 16; j++) Dg[c * 16 + j] = row[CB + j];
    Dinv[c] = 1.0f / row[CB + c];
  }
  __syncthreads();
  if (actv && r >= CB + 16) {
#pragma unroll
    for (int c2 = 0; c2 < 16; c2++) {
      float v = row[CB + c2];
#pragma unroll
      for (int k = 0; k < c2; k++) v -= row[CB + k] * Dg[c2 * 16 + k];
      row[CB + c2] = v * Dinv[c2];
    }
  }
  __syncthreads();
}

__global__ __launch_bounds__(768) void chol_panel(float* __restrict__ Lb, int jb) {
  int p = blockIdx.x;
  float* L = Lb + (size_t)p * 589824;
  int R = 768 - jb;
  int r = threadIdx.x;
  bool actv = r < R;
  __shared__ float Bl[48 * 16];
  __shared__ float Dg[256];
  __shared__ float Dinv[16];
  float row[64];
  float* my = L + (size_t)(jb + r) * 768 + jb;
  if (actv) {
#pragma unroll
    for (int i = 0; i < 16; i++) {
      f4v v = *(const f4v*)(my + 4 * i);
      row[4 * i] = v[0]; row[4 * i + 1] = v[1]; row[4 * i + 2] = v[2]; row[4 * i + 3] = v[3];
    }
  }
  chol_sub<0>(row, r, actv, Bl, Dg, Dinv);
  chol_sub<16>(row, r, actv, Bl, Dg, Dinv);
  chol_sub<32>(row, r, actv, Bl, Dg, Dinv);
  chol_sub<48>(row, r, actv, Bl, Dg, Dinv);
  if (actv) {
#pragma unroll
    for (int i = 0; i < 16; i++) {
      f4v v; v[0] = row[4 * i]; v[1] = row[4 * i + 1]; v[2] = row[4 * i + 2]; v[3] = row[4 * i + 3];
      *(f4v*)(my + 4 * i) = v;
    }
  }
}

// ---------------- L -> Ut (Ut[k][j] = L[j][k] if j>k else 0) + diag ---------
__global__ __launch_bounds__(256) void ltrans_k(const float* __restrict__ Lb,
                                                float* __restrict__ Ut,
                                                float* __restrict__ dg) {
  int p = blockIdx.z;
  const float* L = Lb + (size_t)p * 589824;
  float* U = Ut + (size_t)p * 589824;
  int r0 = blockIdx.x << 5, c0 = blockIdx.y << 5;
  __shared__ float t[32][33];
  int a = threadIdx.x >> 3, b4 = (threadIdx.x & 7) << 2;
  f4v v = *(const f4v*)(L + (size_t)(r0 + a) * 768 + c0 + b4);
  t[a][b4] = v[0]; t[a][b4 + 1] = v[1]; t[a][b4 + 2] = v[2]; t[a][b4 + 3] = v[3];
  __syncthreads();
  int k = c0 + a;
  f4v ov;
#pragma unroll
  for (int i = 0; i < 4; i++) {
    int j = r0 + b4 + i;
    float val = t[b4 + i][a];
    ov[i] = (j > k) ? val : 0.0f;
    if (j == k) dg[p * 768 + k] = val;
  }
  *(f4v*)(U + (size_t)k * 768 + r0 + b4) = ov;
}

// ---------------- column-sweep trsm + logp: 1 wave per (b,p) ----------------
__global__ __launch_bounds__(64) void trsm2(const float* __restrict__ Ut,
                                            const float* __restrict__ dg,
                                            const float* __restrict__ q,
                                            const float* __restrict__ mean,
                                            float* __restrict__ logp) {
  int gw = blockIdx.x;
  int p = gw >> 4, b = gw & 15;
  const float* U = Ut + (size_t)p * 589824;
  int lane = threadIdx.x;

  float y[12], dinv[12];
  float lacc = 0.0f;
#pragma unroll
  for (int m = 0; m < 12; m++) {
    int i = lane + (m << 6);
    y[m] = q[b * 768 + i] - mean[p * 768 + i];
    float d = dg[p * 768 + i];
    dinv[m] = 1.0f / d;
    lacc += __logf(d);
  }

  float u[8][12];
#pragma unroll
  for (int d0 = 0; d0 < 8; d0++)
#pragma unroll
    for (int mm = 0; mm < 12; mm++)
      u[d0][mm] = U[(size_t)d0 * 768 + lane + (mm << 6)];

#pragma unroll
  for (int m = 0; m < 12; m++) {
    for (int kb = 0; kb < 64; kb += 8) {
#pragma unroll
      for (int kd = 0; kd < 8; kd++) {
        int k = (m << 6) + kb + kd;
        float yo = __shfl(y[m], kb + kd, 64);
        float di = __shfl(dinv[m], kb + kd, 64);
        float yk = yo * di;
        if (lane == kb + kd) y[m] = yk;
        // prefetch row k+8 (overwrites slot kd after its use below)
        float un[12];
        bool pf = (k + 8) < 768;
        const float* rp = U + (size_t)(k + 8) * 768 + lane;
#pragma unroll
        for (int mm = 0; mm < 12; mm++) un[mm] = pf ? rp[mm << 6] : 0.0f;
#pragma unroll
        for (int mm = 0; mm < 12; mm++) y[mm] -= u[kd][mm] * yk;
#pragma unroll
        for (int mm = 0; mm < 12; mm++) u[kd][mm] = un[mm];
      }
    }
  }

  float quad = 0.0f;
#pragma unroll
  for (int m = 0; m < 12; m++) quad += y[m] * y[m];
  quad = wred64(quad);
  lacc = wred64(lacc);
  if (lane == 0)
    logp[b * 10 + p] = -0.5f * (768.0f * 1.8378770664093453f + 2.0f * lacc + quad);
}

__global__ void topk_k(const float* __restrict__ logp, int* __restrict__ tk) {
  int b = threadIdx.x;
  if (b >= 16) return;
  float v[10];
#pragma unroll
  for (int p = 0; p < 10; p++) v[p] = logp[b * 10 + p];
#pragma unroll
  for (int s = 0; s < 5; s++) {
    int bi = 0; float bv = v[0];
#pragma unroll
    for (int p = 1; p < 10; p++) if (v[p] > bv) { bv = v[p]; bi = p; }
    tk[b * 5 + s] = bi;
    v[bi] = -3.0e38f;
  }
}

DEV float blocksum256(float s, float* red) {
  s = wred64(s);
  __syncthreads();
  if ((threadIdx.x & 63) == 0) red[threadIdx.x >> 6] = s;
  __syncthreads();
  return red[0] + red[1] + red[2] + red[3];
}

__global__ __launch_bounds__(256) void final_head(const float* __restrict__ x,
                                                  const float* __restrict__ g,
                                                  const float* __restrict__ b,
                                                  const float* __restrict__ hw,
                                                  const float* __restrict__ hb,
                                                  float* __restrict__ out) {
  int bb = blockIdx.x, tid = threadIdx.x;
  __shared__ float xm[768];
  __shared__ float red[4];
  float a0 = 0, a1 = 0, a2 = 0;
  for (int j = 1; j <= 25; j++) {
    const float* rp = x + ((size_t)bb * 222 + j) * 768;
    float v0 = rp[tid], v1 = rp[tid + 256], v2 = rp[tid + 512];
    float s = blocksum256(v0 + v1 + v2, red);
    float mean = s * (1.0f / 768.0f);
    float d0 = v0 - mean, d1 = v1 - mean, d2 = v2 - mean;
    float s2 = blocksum256(d0 * d0 + d1 * d1 + d2 * d2, red);
    float rstd = rsqrtf(s2 * (1.0f / 768.0f) + 1e-6f);
    a0 += d0 * rstd * g[tid] + b[tid];
    a1 += d1 * rstd * g[tid + 256] + b[tid + 256];
    a2 += d2 * rstd * g[tid + 512] + b[tid + 512];
  }
  xm[tid] = a0 * (1.0f / 25.0f);
  xm[tid + 256] = a1 * (1.0f / 25.0f);
  xm[tid + 512] = a2 * (1.0f / 25.0f);
  __syncthreads();
  if (tid < 100) {
    float s = hb[tid];
    for (int d = 0; d < 768; d++) s += xm[d] * hw[d * 100 + tid];
    out[bb * 100 + tid] = s;
  }
}

// ---------------------------------------------------------------------------
extern "C" void kernel_launch(void* const* d_in, const int* in_sizes, int n_in,
                              void* d_out, int out_size, void* d_ws, size_t ws_size,
                              hipStream_t stream) {
  (void)in_sizes; (void)n_in; (void)out_size; (void)ws_size;
  const float* inp     = (const float*)d_in[0];
  const float* patchw  = (const float*)d_in[1];
  const float* patchb  = (const float*)d_in[2];
  const float* cls     = (const float*)d_in[3];
  const float* pos     = (const float*)d_in[4];
  const float* ln1g    = (const float*)d_in[5];
  const float* ln1b    = (const float*)d_in[6];
  const float* qkvw    = (const float*)d_in[7];
  const float* qkvb    = (const float*)d_in[8];
  const float* projw   = (const float*)d_in[9];
  const float* projb   = (const float*)d_in[10];
  const float* ln2g    = (const float*)d_in[11];
  const float* ln2b    = (const float*)d_in[12];
  const float* fc1w    = (const float*)d_in[13];
  const float* fc1b    = (const float*)d_in[14];
  const float* fc2w    = (const float*)d_in[15];
  const float* fc2b    = (const float*)d_in[16];
  const float* normg   = (const float*)d_in[17];
  const float* normb   = (const float*)d_in[18];
  const float* headw   = (const float*)d_in[19];
  const float* headb   = (const float*)d_in[20];
  const float* prompt  = (const float*)d_in[21];
  const float* meanp   = (const float*)d_in[22];
  const float* var     = (const float*)d_in[23];
  float* out = (float*)d_out;

  char* ws = (char*)d_ws;
  size_t cur = 0;
  auto alloc = [&](size_t bytes) { size_t r = cur; cur += (bytes + 255) & ~(size_t)255; return r; };
  float* x    = (float*)(ws + alloc((size_t)3552 * 768 * 4));
  float* img  = (float*)(ws + alloc((size_t)3136 * 768 * 4));
  float* qb   = (float*)(ws + alloc((size_t)16 * 768 * 4));
  float* logp = (float*)(ws + alloc(1024));
  int*   tk   = (int*)(ws + alloc(1024));
  float* dg   = (float*)(ws + alloc((size_t)10 * 768 * 4));
  h16_t* h16   = (h16_t*)(ws + alloc((size_t)3552 * 768 * 2));
  size_t qkv_off = alloc((size_t)3552 * 2304 * 2);
  h16_t* qkv16 = (h16_t*)(ws + qkv_off);
  size_t g_off = alloc((size_t)3552 * 3072 * 2);
  h16_t* g16   = (h16_t*)(ws + g_off);
  float* Lbuf  = (float*)(ws + alloc((size_t)10 * 589824 * 4));
  h16_t* wq16  = (h16_t*)(ws + alloc((size_t)12 * 2304 * 768 * 2));
  h16_t* wp16  = (h16_t*)(ws + alloc((size_t)12 * 768 * 768 * 2));
  h16_t* w116  = (h16_t*)(ws + alloc((size_t)12 * 3072 * 768 * 2));
  h16_t* w216  = (h16_t*)(ws + alloc((size_t)12 * 768 * 3072 * 2));
  h16_t* wpt16 = (h16_t*)(ws + alloc((size_t)768 * 768 * 2));
  // phase-disjoint aliases:
  h16_t* col16 = (h16_t*)(ws + g_off);   // im2col (before pass 1)
  float* Ut    = (float*)(ws + qkv_off); // 23.6 MB over qkv16+g16 (MVN phase)

  // -------- weight conversion / transposition (fp32 [K,N] -> fp16 [N,K])
  wcvt_t<<<dim3(72, 24, 12), 256, 0, stream>>>(qkvw, wq16, 768, 2304);
  wcvt_t<<<dim3(24, 24, 12), 256, 0, stream>>>(projw, wp16, 768, 768);
  wcvt_t<<<dim3(96, 24, 12), 256, 0, stream>>>(fc1w, w116, 768, 3072);
  wcvt_t<<<dim3(24, 96, 12), 256, 0, stream>>>(fc2w, w216, 3072, 768);
  cvt_flat<<<2304, 256, 0, stream>>>(patchw, wpt16, 589824);

  // -------- patch embed + x0
  im2col_k<<<9408, 256, 0, stream>>>(inp, col16);
  hgemm_p<<<dim3(25, 6), 512, 0, stream>>>(col16, wpt16, img, patchb,
      3136, 768, 768, 768, 0);
  build_x0_k<<<9456, 256, 0, stream>>>(x, img, cls, pos);

  auto pass = [&](int Ntok) {
    int M = 16 * Ntok;
    int Mt1 = (M + 127) / 128;
    int Mt8 = (M + 255) / 256;
    int Qt = (Ntok + 63) / 64;
    for (int l = 0; l < 12; l++) {
      ln_rows<<<(M + 3) / 4, 256, 0, stream>>>(x, h16, nullptr, ln1g + l * 768, ln1b + l * 768, M, 768, 768);
      hgemm_q<<<dim3(Mt1, 9), 512, 0, stream>>>(h16, wq16 + (size_t)l * 2304 * 768, qkv16,
          qkvb + l * 2304, M, 2304, 768, 2304);
      flash_attn<<<dim3(Qt, 192), 256, 0, stream>>>(qkv16, h16, Ntok);
      hgemm_p<<<dim3(Mt1, 6), 512, 0, stream>>>(h16, wp16 + (size_t)l * 768 * 768, x,
          projb + l * 768, M, 768, 768, 768, 1);
      ln_rows<<<(M + 3) / 4, 256, 0, stream>>>(x, h16, nullptr, ln2g + l * 768, ln2b + l * 768, M, 768, 768);
      hgemm_f<<<dim3(Mt8, 12), 512, 0, stream>>>(h16, w116 + (size_t)l * 3072 * 768, g16,
          fc1b + l * 3072, M, 3072, 768, 3072);
      hgemm_p<<<dim3(Mt1, 6), 512, 0, stream>>>(g16, w216 + (size_t)l * 768 * 3072, x,
          fc2b + l * 768, M, 768, 3072, 768, 1);
    }
  };

  // -------- query pass, q = LN(x)[:,0]
  pass(197);
  ln_rows<<<4, 256, 0, stream>>>(x, nullptr, qb, normg, normb, 16, (long)197 * 768, 768);

  // -------- cov = |var| + I ; blocked Cholesky (NB=64) ; logp ; topk
  cov_init_k<<<23040, 256, 0, stream>>>(var, Lbuf);
  for (int m = 0; m < 12; m++) {
    int jb = 64 * m;
    if (m) sgemm_nt_chol<<<dim3((768 - jb) / 64, 1, 10), 256, 0, stream>>>(Lbuf, jb);
    chol_panel<<<10, 768, 0, stream>>>(Lbuf, jb);
  }
  ltrans_k<<<dim3(24, 24, 10), 256, 0, stream>>>(Lbuf, Ut, dg);
  trsm2<<<160, 64, 0, stream>>>(Ut, dg, qb, meanp, logp);
  topk_k<<<1, 64, 0, stream>>>(logp, tk);

  // -------- prompted pass + head
  build_x2_k<<<10656, 256, 0, stream>>>(x, img, cls, pos, prompt, tk);
  pass(222);
  final_head<<<16, 256, 0, stream>>>(x, normg, normb, headw, headb, out);
}